// Round 1
// baseline (1201.264 us; speedup 1.0000x reference)
//
#include <hip/hip_runtime.h>

// ---------------- generic f32 tiled GEMM: C[M,:] (ldc, col offset) = A[M,K] @ B[K,Nb] (+bias) (*rowscale)
constexpr int GBM = 128, GBN = 64, GBK = 16, GTM = 8, GTN = 4;

__global__ __launch_bounds__(256)
void gemm_kernel(const float* __restrict__ A, const float* __restrict__ B,
                 const float* __restrict__ bias, const float* __restrict__ rowscale,
                 float* __restrict__ C, int M, int Nb, int K, int ldc, int ccol)
{
    __shared__ float As[GBK][GBM + 4];
    __shared__ float Bs[GBK][GBN];
    const int t = threadIdx.x;
    const int tx = t & 15, ty = t >> 4;
    const int row0 = blockIdx.x * GBM;
    const int col0 = blockIdx.y * GBN;
    float acc[GTM][GTN] = {};
    for (int k0 = 0; k0 < K; k0 += GBK) {
        // A tile: 128x16 = 512 float4, 2 per thread (K is always a multiple of 16 here)
#pragma unroll
        for (int s = 0; s < 2; ++s) {
            int idx4 = t + s * 256;
            int m = idx4 >> 2, k4 = (idx4 & 3) << 2;
            int gm = row0 + m;
            float4 av = make_float4(0.f, 0.f, 0.f, 0.f);
            if (gm < M) av = *reinterpret_cast<const float4*>(A + (size_t)gm * K + k0 + k4);
            As[k4 + 0][m] = av.x; As[k4 + 1][m] = av.y; As[k4 + 2][m] = av.z; As[k4 + 3][m] = av.w;
        }
        // B tile: 16x64 = 256 float4, 1 per thread
        {
            int kk = t >> 4, n4 = (t & 15) << 2;
            float4 bv = *reinterpret_cast<const float4*>(B + (size_t)(k0 + kk) * Nb + col0 + n4);
            *reinterpret_cast<float4*>(&Bs[kk][n4]) = bv;
        }
        __syncthreads();
#pragma unroll
        for (int kk = 0; kk < GBK; ++kk) {
            float a[GTM], b[GTN];
#pragma unroll
            for (int i = 0; i < GTM; ++i) a[i] = As[kk][ty * GTM + i];
#pragma unroll
            for (int j = 0; j < GTN; ++j) b[j] = Bs[kk][tx * GTN + j];
#pragma unroll
            for (int i = 0; i < GTM; ++i)
#pragma unroll
                for (int j = 0; j < GTN; ++j)
                    acc[i][j] += a[i] * b[j];
        }
        __syncthreads();
    }
#pragma unroll
    for (int i = 0; i < GTM; ++i) {
        int gm = row0 + ty * GTM + i;
        if (gm >= M) break;
        float rs = rowscale ? rowscale[gm] : 1.f;
        float4 v = make_float4(acc[i][0], acc[i][1], acc[i][2], acc[i][3]);
        if (bias) {
            const float* bp = bias + col0 + tx * GTN;
            v.x += bp[0]; v.y += bp[1]; v.z += bp[2]; v.w += bp[3];
        }
        v.x *= rs; v.y *= rs; v.z *= rs; v.w *= rs;
        *reinterpret_cast<float4*>(C + (size_t)gm * ldc + ccol + col0 + tx * GTN) = v;
    }
}

// ---------------- graph preprocessing
__global__ void deg_kernel(const int* __restrict__ src, const int* __restrict__ dst,
                           int* degout, int* degin, int E)
{
    int e = blockIdx.x * blockDim.x + threadIdx.x;
    if (e < E) {
        atomicAdd(&degout[src[e]], 1);
        atomicAdd(&degin[dst[e]], 1);
    }
}

__global__ __launch_bounds__(1024)
void scan_kernel(const int* __restrict__ degin, int* __restrict__ rowstart, int n)
{
    __shared__ int part[1024];
    int t = threadIdx.x;
    int chunk = (n + 1023) / 1024;
    int s = 0;
    for (int i = 0; i < chunk; ++i) {
        int idx = t * chunk + i;
        if (idx < n) s += degin[idx];
    }
    part[t] = s;
    __syncthreads();
    for (int o = 1; o < 1024; o <<= 1) {
        int v = (t >= o) ? part[t - o] : 0;
        __syncthreads();
        part[t] += v;
        __syncthreads();
    }
    int run = (t > 0) ? part[t - 1] : 0;
    for (int i = 0; i < chunk; ++i) {
        int idx = t * chunk + i;
        if (idx < n) { rowstart[idx] = run; run += degin[idx]; }
    }
    if (t == 1023) rowstart[n] = part[1023];
}

__global__ void perm_kernel(const int* __restrict__ dst, const int* __restrict__ rowstart,
                            int* cursor, int* __restrict__ perm, int E)
{
    int e = blockIdx.x * blockDim.x + threadIdx.x;
    if (e < E) {
        int v = dst[e];
        int p = atomicAdd(&cursor[v], 1);
        perm[rowstart[v] + p] = e;
    }
}

__global__ void rs_kernel(const int* degout, const int* degin, float* rso, float* rsi, int n)
{
    int i = blockIdx.x * blockDim.x + threadIdx.x;
    if (i < n) {
        rso[i] = rsqrtf((float)max(degout[i], 1));
        rsi[i] = rsqrtf((float)max(degin[i], 1));
    }
}

// ---------------- LSTM
__global__ void lstm_pre(const float* __restrict__ x, const float* __restrict__ Wf,
                         const float* __restrict__ Wb,
                         const float* bf1, const float* bf2, const float* bb1, const float* bb2,
                         float* __restrict__ xWf, float* __restrict__ xWb, int n)
{
    int gid = blockIdx.x * blockDim.x + threadIdx.x;
    if (gid >= n * 32) return;
    int nn = gid >> 5, r = gid & 31, d = r >> 4, j = r & 15;
    const float* W = (d ? Wb : Wf) + j * 192;
    const float* xr = x + (size_t)nn * 192;
    float s = 0.f;
#pragma unroll 4
    for (int k = 0; k < 192; k += 4) {
        float4 xv = *reinterpret_cast<const float4*>(xr + k);
        float4 wv = *reinterpret_cast<const float4*>(W + k);
        s += xv.x * wv.x + xv.y * wv.y + xv.z * wv.z + xv.w * wv.w;
    }
    s += d ? (bb1[j] + bb2[j]) : (bf1[j] + bf2[j]);
    (d ? xWb : xWf)[(size_t)nn * 16 + j] = s;
}

__device__ __forceinline__ float sigm(float x) { return 1.f / (1.f + expf(-x)); }

__global__ void lstm_seq(const float* __restrict__ xWf, const float* __restrict__ xWb,
                         const float* __restrict__ Whhf, const float* __restrict__ Whhb,
                         float* __restrict__ newF, int B)
{
    __shared__ float Wh[2][64];
    int t = threadIdx.x;
    if (t < 64) { Wh[0][t] = Whhf[t]; Wh[1][t] = Whhb[t]; }
    __syncthreads();
    if (t >= 2 * B) return;
    int d = (t < B) ? 0 : 1;
    int b = (t < B) ? t : (t - B);
    const float* xW = d ? xWb : xWf;
    float h[4] = {0, 0, 0, 0}, c[4] = {0, 0, 0, 0};
    for (int step = 0; step < 120; ++step) {
        int tt = d ? (119 - step) : step;
        size_t nidx = (size_t)b * 120 + tt;
        const float* z0 = xW + nidx * 16;
        float z[16];
#pragma unroll
        for (int j = 0; j < 16; ++j) {
            float s = z0[j];
#pragma unroll
            for (int k = 0; k < 4; ++k) s += Wh[d][j * 4 + k] * h[k];
            z[j] = s;
        }
#pragma unroll
        for (int k = 0; k < 4; ++k) {
            float ig = sigm(z[k]);
            float fg = sigm(z[4 + k]);
            float gg = tanhf(z[8 + k]);
            float og = sigm(z[12 + k]);
            c[k] = fg * c[k] + ig * gg;
            h[k] = og * tanhf(c[k]);
        }
        float* o = newF + nidx * 8 + d * 4;
#pragma unroll
        for (int k = 0; k < 4; ++k) o[k] = h[k];
    }
}

// ---------------- GraphConv combine + L1 norm
__global__ __launch_bounds__(192)
void gc_combine(const float* __restrict__ stackFT, const float* __restrict__ hw,
                const int* __restrict__ rowstart, const int* __restrict__ perm,
                const int* __restrict__ srcidx, const float* __restrict__ rs_in,
                const float* __restrict__ b_gc, float* __restrict__ h, int n)
{
    int v = blockIdx.x;
    int f = threadIdx.x;
    int s0 = rowstart[v], s1 = rowstart[v + 1];
    float s = 0.f;
    for (int i = s0; i < s1; ++i) {
        int u = srcidx[perm[i]];
        s += hw[(size_t)u * 192 + f];
    }
    float val = 0.5f * (stackFT[(size_t)v * 192 + f] + s * rs_in[v] + b_gc[f]);
    __shared__ float red[192];
    red[f] = fabsf(val);
    __syncthreads();
    if (f < 64) red[f] = red[f] + red[f + 64] + red[f + 128];
    __syncthreads();
    if (f < 64) {
        float r = red[f];
        for (int o = 32; o; o >>= 1) r += __shfl_down(r, o, 64);
        if (f == 0) red[0] = r;
    }
    __syncthreads();
    float denom = fmaxf(red[0], 1e-12f);
    h[(size_t)v * 192 + f] = val / denom;
}

// ---------------- GATv2 edge pass (CSR, one block per dst node), H=16 heads
template <int F>
__global__ void gat_edge(const float* __restrict__ fs, const float* __restrict__ fd,
                         const float* __restrict__ attn,
                         const int* __restrict__ rowstart, const int* __restrict__ perm,
                         const int* __restrict__ srcidx,
                         float* __restrict__ num, float* __restrict__ den, int n)
{
    constexpr int HF = 16 * F;
    int v = blockIdx.x;
    int t = threadIdx.x;
    float fdv = fd[(size_t)v * HF + t];
    float at = attn[t];
    float acc = 0.f, dn = 0.f;
    int s0 = rowstart[v], s1 = rowstart[v + 1];
    for (int i = s0; i < s1; ++i) {
        int u = srcidx[perm[i]];
        float sv = fs[(size_t)u * HF + t];
        float w = sv + fdv;
        w = (w > 0.f) ? w : 0.2f * w;
        float p = w * at;
#pragma unroll
        for (int o = F >> 1; o; o >>= 1) p += __shfl_xor(p, o, F);
        float ex = expf(p);
        acc += ex * sv;
        dn += ex;
    }
    num[(size_t)v * HF + t] = acc;
    if ((t & (F - 1)) == 0) den[(size_t)v * 16 + t / F] = dn;
}

__global__ void gat_fin(const float* __restrict__ den, const float* __restrict__ res,
                        float* __restrict__ num, int HF, int F, int total)
{
    int i = blockIdx.x * blockDim.x + threadIdx.x;
    if (i >= total) return;
    int v = i / HF, t = i - v * HF, h = t / F;
    float d = den[(size_t)v * 16 + h];
    float o = (d > 0.f) ? num[i] / d : 0.f;
    num[i] = fmaxf(o + res[i], 0.f);
}

// ---------------- final classifier
__global__ void final_lin(const float* __restrict__ h1, const float* __restrict__ newF,
                          const float* __restrict__ h3, const float* __restrict__ W,
                          const float* __restrict__ bias, float* __restrict__ out, int n)
{
    int gid = blockIdx.x * blockDim.x + threadIdx.x;
    if (gid >= n * 6) return;
    int v = gid / 6, o = gid - v * 6;
    float s = bias[o];
    const float* a = h1 + (size_t)v * 64;
#pragma unroll 8
    for (int r = 0; r < 64; ++r) s += a[r] * W[r * 6 + o];
    const float* b = newF + (size_t)v * 8;
#pragma unroll
    for (int r = 0; r < 8; ++r) s += b[r] * W[(64 + r) * 6 + o];
    const float* c = h3 + (size_t)v * 64;
#pragma unroll 8
    for (int r = 0; r < 64; ++r) s += c[r] * W[(72 + r) * 6 + o];
    out[gid] = s;
}

// ----------------------------------------------------------------------------
extern "C" void kernel_launch(void* const* d_in, const int* in_sizes, int n_in,
                              void* d_out, int out_size, void* d_ws, size_t ws_size,
                              hipStream_t stream)
{
    const float* text   = (const float*)d_in[0];
    const float* audio  = (const float*)d_in[1];
    const float* vision = (const float*)d_in[2];
    const int*   esrc   = (const int*)d_in[3];
    const int*   edst   = (const int*)d_in[4];
    const float* W_audio = (const float*)d_in[5];  const float* b_audio = (const float*)d_in[6];
    const float* W_vision= (const float*)d_in[7];  const float* b_vision= (const float*)d_in[8];
    const float* W_text  = (const float*)d_in[9];  const float* b_text  = (const float*)d_in[10];
    const float* Wih_f = (const float*)d_in[11]; const float* Whh_f = (const float*)d_in[12];
    const float* bih_f = (const float*)d_in[13]; const float* bhh_f = (const float*)d_in[14];
    const float* Wih_b = (const float*)d_in[15]; const float* Whh_b = (const float*)d_in[16];
    const float* bih_b = (const float*)d_in[17]; const float* bhh_b = (const float*)d_in[18];
    const float* W_gc  = (const float*)d_in[19]; const float* b_gc  = (const float*)d_in[20];
    const float* Wsrc2 = (const float*)d_in[21]; const float* bsrc2 = (const float*)d_in[22];
    const float* Wdst2 = (const float*)d_in[23]; const float* bdst2 = (const float*)d_in[24];
    const float* attn2 = (const float*)d_in[25]; const float* Wres2 = (const float*)d_in[26];
    const float* Wsrc0 = (const float*)d_in[27]; const float* bsrc0 = (const float*)d_in[28];
    const float* Wdst0 = (const float*)d_in[29]; const float* bdst0 = (const float*)d_in[30];
    const float* attn0 = (const float*)d_in[31]; const float* Wres0 = (const float*)d_in[32];
    const float* Wsrc1 = (const float*)d_in[33]; const float* bsrc1 = (const float*)d_in[34];
    const float* Wdst1 = (const float*)d_in[35]; const float* bdst1 = (const float*)d_in[36];
    const float* attn1 = (const float*)d_in[37]; const float* Wres1 = (const float*)d_in[38];
    const float* W_lin = (const float*)d_in[39]; const float* b_lin = (const float*)d_in[40];
    float* out = (float*)d_out;

    const int n = in_sizes[0] / 1024;   // 12000
    const int E = in_sizes[3];          // 192000

    // ---- workspace carve (all 256B aligned)
    char* p = (char*)d_ws;
    auto alloc_f = [&](size_t cnt) { float* r = (float*)p; p += ((cnt * 4 + 255) / 256) * 256; return r; };
    auto alloc_i = [&](size_t cnt) { int* r = (int*)p; p += ((cnt * 4 + 255) / 256) * 256; return r; };
    float* stackFT = alloc_f((size_t)n * 192);
    float* hbuf    = alloc_f((size_t)n * 192);
    float* xWf     = alloc_f((size_t)n * 16);
    float* xWb     = alloc_f((size_t)n * 16);
    float* newF    = alloc_f((size_t)n * 8);
    float* big0    = alloc_f((size_t)n * 512);   // fs / hw
    float* big1    = alloc_f((size_t)n * 512);   // fd, then res
    float* big2    = alloc_f((size_t)n * 512);   // num0 -> h0
    float* den     = alloc_f((size_t)n * 16);
    float* h3      = alloc_f((size_t)n * 64);
    float* h1s     = alloc_f((size_t)n * 64);
    float* rs_out  = alloc_f(n);
    float* rs_in   = alloc_f(n);
    int* zero_base = alloc_i((size_t)3 * n);     // degout, degin, cursor
    int* degout = zero_base;
    int* degin  = zero_base + n;
    int* cursor = zero_base + 2 * n;
    int* rowstart = alloc_i((size_t)n + 1);
    int* perm     = alloc_i((size_t)E);
    if ((size_t)(p - (char*)d_ws) > ws_size) return;  // refuse to corrupt memory

    // ---- graph preprocessing (CSR by dst)
    hipMemsetAsync(zero_base, 0, (size_t)3 * n * 4, stream);
    deg_kernel<<<(E + 255) / 256, 256, 0, stream>>>(esrc, edst, degout, degin, E);
    scan_kernel<<<1, 1024, 0, stream>>>(degin, rowstart, n);
    perm_kernel<<<(E + 255) / 256, 256, 0, stream>>>(edst, rowstart, cursor, perm, E);
    rs_kernel<<<(n + 255) / 256, 256, 0, stream>>>(degout, degin, rs_out, rs_in, n);

    auto gemm = [&](const float* A, const float* B, const float* bias, const float* rsc,
                    float* C, int M, int Nb, int K, int ldc, int ccol) {
        dim3 grid((M + GBM - 1) / GBM, Nb / GBN);
        gemm_kernel<<<grid, 256, 0, stream>>>(A, B, bias, rsc, C, M, Nb, K, ldc, ccol);
    };

    // ---- modality encoders -> stackFT [n,192]
    gemm(text,   W_text,   b_text,   nullptr, stackFT, n, 64, 1024, 192, 0);
    gemm(audio,  W_audio,  b_audio,  nullptr, stackFT, n, 64, 512,  192, 64);
    gemm(vision, W_vision, b_vision, nullptr, stackFT, n, 64, 1024, 192, 128);

    // ---- BiLSTM
    lstm_pre<<<(n * 32 + 255) / 256, 256, 0, stream>>>(stackFT, Wih_f, Wih_b,
                                                       bih_f, bhh_f, bih_b, bhh_b, xWf, xWb, n);
    lstm_seq<<<1, 256, 0, stream>>>(xWf, xWb, Whh_f, Whh_b, newF, n / 120);

    // ---- GraphConv imputation + L1 norm -> hbuf [n,192]
    gemm(stackFT, W_gc, nullptr, rs_out, big0, n, 192, 192, 192, 0);
    gc_combine<<<n, 192, 0, stream>>>(stackFT, big0, rowstart, perm, esrc, rs_in, b_gc, hbuf, n);

    // ---- gat2 (h -> h3 [n,64], F=4)
    gemm(hbuf, Wsrc2, bsrc2, nullptr, big0, n, 64, 192, 64, 0);
    gemm(hbuf, Wdst2, bdst2, nullptr, big1, n, 64, 192, 64, 0);
    gat_edge<4><<<n, 64, 0, stream>>>(big0, big1, attn2, rowstart, perm, esrc, h3, den, n);
    gemm(hbuf, Wres2, nullptr, nullptr, big1, n, 64, 192, 64, 0);
    gat_fin<<<(n * 64 + 255) / 256, 256, 0, stream>>>(den, big1, h3, 64, 4, n * 64);

    // ---- gat0 (h -> h0 [n,512] in big2, F=32)
    gemm(hbuf, Wsrc0, bsrc0, nullptr, big0, n, 512, 192, 512, 0);
    gemm(hbuf, Wdst0, bdst0, nullptr, big1, n, 512, 192, 512, 0);
    gat_edge<32><<<n, 512, 0, stream>>>(big0, big1, attn0, rowstart, perm, esrc, big2, den, n);
    gemm(hbuf, Wres0, nullptr, nullptr, big1, n, 512, 192, 512, 0);
    gat_fin<<<(n * 512 + 255) / 256, 256, 0, stream>>>(den, big1, big2, 512, 32, n * 512);

    // ---- gat1 (h0 -> h1 [n,64], F=4)
    gemm(big2, Wsrc1, bsrc1, nullptr, big0, n, 64, 512, 64, 0);
    gemm(big2, Wdst1, bdst1, nullptr, big1, n, 64, 512, 64, 0);
    gat_edge<4><<<n, 64, 0, stream>>>(big0, big1, attn1, rowstart, perm, esrc, h1s, den, n);
    gemm(big2, Wres1, nullptr, nullptr, big1, n, 64, 512, 64, 0);
    gat_fin<<<(n * 64 + 255) / 256, 256, 0, stream>>>(den, big1, h1s, 64, 4, n * 64);

    // ---- final classifier
    final_lin<<<(n * 6 + 255) / 256, 256, 0, stream>>>(h1s, newF, h3, W_lin, b_lin, out, n);
}

// Round 2
// 681.618 us; speedup vs baseline: 1.7624x; 1.7624x over previous
//
#include <hip/hip_runtime.h>

// ---------------- generic f32 tiled GEMM body: C[M rows] = A[M,K] @ B[K,Nb] (+bias) (*rowscale)
template<int BM, int TM>
__device__ __forceinline__ void gemm_body(const float* __restrict__ A, const float* __restrict__ B,
                                          const float* __restrict__ bias, const float* __restrict__ rowscale,
                                          float* __restrict__ C, int M, int Nb, int K, int ldc, int ccol,
                                          int bx, int by)
{
    __shared__ float As[16][BM + 4];
    __shared__ float Bs[16][64];
    const int t = threadIdx.x;
    const int tx = t & 15, ty = t >> 4;
    const int row0 = bx * BM;
    const int col0 = by * 64;
    float acc[TM][4] = {};
    for (int k0 = 0; k0 < K; k0 += 16) {
#pragma unroll
        for (int s = 0; s < BM / 64; ++s) {
            int idx4 = t + s * 256;
            int m = idx4 >> 2, k4 = (idx4 & 3) << 2;
            int gm = row0 + m;
            float4 av = make_float4(0.f, 0.f, 0.f, 0.f);
            if (gm < M) av = *reinterpret_cast<const float4*>(A + (size_t)gm * K + k0 + k4);
            As[k4 + 0][m] = av.x; As[k4 + 1][m] = av.y; As[k4 + 2][m] = av.z; As[k4 + 3][m] = av.w;
        }
        {
            int kk = t >> 4, n4 = (t & 15) << 2;
            float4 bv = *reinterpret_cast<const float4*>(B + (size_t)(k0 + kk) * Nb + col0 + n4);
            *reinterpret_cast<float4*>(&Bs[kk][n4]) = bv;
        }
        __syncthreads();
#pragma unroll
        for (int kk = 0; kk < 16; ++kk) {
            float4 bv = *reinterpret_cast<const float4*>(&Bs[kk][tx * 4]);
            float av[TM];
#pragma unroll
            for (int i = 0; i < TM / 4; ++i) {
                float4 a4 = *reinterpret_cast<const float4*>(&As[kk][ty * TM + i * 4]);
                av[i * 4 + 0] = a4.x; av[i * 4 + 1] = a4.y; av[i * 4 + 2] = a4.z; av[i * 4 + 3] = a4.w;
            }
#pragma unroll
            for (int i = 0; i < TM; ++i) {
                acc[i][0] += av[i] * bv.x; acc[i][1] += av[i] * bv.y;
                acc[i][2] += av[i] * bv.z; acc[i][3] += av[i] * bv.w;
            }
        }
        __syncthreads();
    }
#pragma unroll
    for (int i = 0; i < TM; ++i) {
        int gm = row0 + ty * TM + i;
        if (gm >= M) break;
        float rs = rowscale ? rowscale[gm] : 1.f;
        float4 v = make_float4(acc[i][0], acc[i][1], acc[i][2], acc[i][3]);
        if (bias) {
            const float* bp = bias + col0 + tx * 4;
            v.x += bp[0]; v.y += bp[1]; v.z += bp[2]; v.w += bp[3];
        }
        v.x *= rs; v.y *= rs; v.z *= rs; v.w *= rs;
        *reinterpret_cast<float4*>(C + (size_t)gm * ldc + ccol + col0 + tx * 4) = v;
    }
}

template<int BM, int TM>
__global__ __launch_bounds__(256)
void gemm_kernel(const float* __restrict__ A, const float* __restrict__ B,
                 const float* __restrict__ bias, const float* __restrict__ rowscale,
                 float* __restrict__ C, int M, int Nb, int K, int ldc, int ccol)
{
    gemm_body<BM, TM>(A, B, bias, rowscale, C, M, Nb, K, ldc, ccol, blockIdx.x, blockIdx.y);
}

// fused 3-modality encoder GEMM (blockIdx.z selects modality)
__global__ __launch_bounds__(256)
void enc3_kernel(const float* __restrict__ text, const float* __restrict__ audio, const float* __restrict__ vision,
                 const float* __restrict__ Wt, const float* __restrict__ Wa, const float* __restrict__ Wv,
                 const float* __restrict__ bt, const float* __restrict__ ba, const float* __restrict__ bv,
                 float* __restrict__ C, int M)
{
    int z = blockIdx.z;
    const float* A  = (z == 0) ? text : (z == 1) ? audio : vision;
    const float* Bm = (z == 0) ? Wt   : (z == 1) ? Wa    : Wv;
    const float* bb = (z == 0) ? bt   : (z == 1) ? ba    : bv;
    int K = (z == 1) ? 512 : 1024;
    gemm_body<64, 4>(A, Bm, bb, nullptr, C, M, 64, K, 192, z * 64, blockIdx.x, 0);
}

// ---------------- weight packing
__global__ void pack3_kernel(const float* __restrict__ W0, const float* __restrict__ W1, const float* __restrict__ W2,
                             const float* __restrict__ b0, const float* __restrict__ b1,
                             float* __restrict__ Wp, float* __restrict__ bp, int K, int O)
{
    int gid = blockIdx.x * blockDim.x + threadIdx.x;
    int O3 = 3 * O;
    if (gid < O3) bp[gid] = (gid < O) ? b0[gid] : (gid < 2 * O) ? b1[gid - O] : 0.f;
    if (gid >= K * O3) return;
    int k = gid / O3, c = gid - k * O3;
    float v = (c < O) ? W0[k * O + c] : (c < 2 * O) ? W1[k * O + c - O] : W2[k * O + c - 2 * O];
    Wp[gid] = v;
}

__global__ void pack2_kernel(const float* __restrict__ W0, const float* __restrict__ W1,
                             const float* __restrict__ b0, const float* __restrict__ b1,
                             float* __restrict__ Wp, float* __restrict__ bp, int K, int O)
{
    int gid = blockIdx.x * blockDim.x + threadIdx.x;
    int O2 = 2 * O;
    if (gid < O2) bp[gid] = (gid < O) ? b0[gid] : b1[gid - O];
    if (gid >= K * O2) return;
    int k = gid / O2, c = gid - k * O2;
    Wp[gid] = (c < O) ? W0[k * O + c] : W1[k * O + c - O];
}

// ---------------- graph preprocessing
__global__ void deg_kernel(const int* __restrict__ src, const int* __restrict__ dst,
                           int* degout, int* degin, int E)
{
    int e = blockIdx.x * blockDim.x + threadIdx.x;
    if (e < E) {
        atomicAdd(&degout[src[e]], 1);
        atomicAdd(&degin[dst[e]], 1);
    }
}

__global__ __launch_bounds__(1024)
void scan_kernel(const int* __restrict__ degin, int* __restrict__ rowstart, int n)
{
    __shared__ int part[1024];
    int t = threadIdx.x;
    int chunk = (n + 1023) / 1024;
    int s = 0;
    for (int i = 0; i < chunk; ++i) {
        int idx = t * chunk + i;
        if (idx < n) s += degin[idx];
    }
    part[t] = s;
    __syncthreads();
    for (int o = 1; o < 1024; o <<= 1) {
        int v = (t >= o) ? part[t - o] : 0;
        __syncthreads();
        part[t] += v;
        __syncthreads();
    }
    int run = (t > 0) ? part[t - 1] : 0;
    for (int i = 0; i < chunk; ++i) {
        int idx = t * chunk + i;
        if (idx < n) { rowstart[idx] = run; run += degin[idx]; }
    }
    if (t == 1023) rowstart[n] = part[1023];
}

__global__ void perm_kernel(const int* __restrict__ dst, const int* __restrict__ rowstart,
                            int* cursor, int* __restrict__ perm, int E)
{
    int e = blockIdx.x * blockDim.x + threadIdx.x;
    if (e < E) {
        int v = dst[e];
        int p = atomicAdd(&cursor[v], 1);
        perm[rowstart[v] + p] = e;
    }
}

// in-place: perm[i] <- esrc[perm[i]]   (thread i owns slot i, no hazard)
__global__ void gather_src_kernel(const int* __restrict__ esrc, int* perm, int E)
{
    int i = blockIdx.x * blockDim.x + threadIdx.x;
    if (i < E) perm[i] = esrc[perm[i]];
}

__global__ void rs_kernel(const int* degout, const int* degin, float* rso, float* rsi, int n)
{
    int i = blockIdx.x * blockDim.x + threadIdx.x;
    if (i < n) {
        rso[i] = rsqrtf((float)max(degout[i], 1));
        rsi[i] = rsqrtf((float)max(degin[i], 1));
    }
}

// ---------------- LSTM
// lstm_pre writes TRANSPOSED per-direction layout: xW[(b*16 + j)*120 + t]
__global__ void lstm_pre(const float* __restrict__ x, const float* __restrict__ Wf,
                         const float* __restrict__ Wb,
                         const float* bf1, const float* bf2, const float* bb1, const float* bb2,
                         float* __restrict__ xWf, float* __restrict__ xWb, int n)
{
    int gid = blockIdx.x * blockDim.x + threadIdx.x;
    if (gid >= n * 32) return;
    int nn = gid >> 5, r = gid & 31, d = r >> 4, j = r & 15;
    const float* W = (d ? Wb : Wf) + j * 192;
    const float* xr = x + (size_t)nn * 192;
    float s = 0.f;
#pragma unroll 4
    for (int k = 0; k < 192; k += 4) {
        float4 xv = *reinterpret_cast<const float4*>(xr + k);
        float4 wv = *reinterpret_cast<const float4*>(W + k);
        s += xv.x * wv.x + xv.y * wv.y + xv.z * wv.z + xv.w * wv.w;
    }
    s += d ? (bb1[j] + bb2[j]) : (bf1[j] + bf2[j]);
    int b = nn / 120, tt = nn - b * 120;
    (d ? xWb : xWf)[((size_t)b * 16 + j) * 120 + tt] = s;
}

__device__ __forceinline__ float fsigm(float x) { return __fdividef(1.f, 1.f + __expf(-x)); }
__device__ __forceinline__ float ftanh(float x) { return 1.f - __fdividef(2.f, __expf(2.f * x) + 1.f); }

// one chain = 16 lanes; lane j owns gate row j; cell state for k=j&3 tracked redundantly
template<int DIR>
__device__ void lstm_chain(const float* __restrict__ xw, const float* __restrict__ whh,
                           float* __restrict__ newF, int b)
{
    int j = threadIdx.x & 15;
    int k = j & 3;
    float4 w = *reinterpret_cast<const float4*>(whh + j * 4);
    const float* xp = xw + ((size_t)b * 16 + j) * 120;
    float h0 = 0.f, h1 = 0.f, h2 = 0.f, h3 = 0.f, cst = 0.f;
    int tb0 = DIR ? 108 : 0;
    float4 a0 = *reinterpret_cast<const float4*>(xp + tb0);
    float4 a1 = *reinterpret_cast<const float4*>(xp + tb0 + 4);
    float4 a2 = *reinterpret_cast<const float4*>(xp + tb0 + 8);
    for (int ch = 0; ch < 10; ++ch) {
        float4 b0 = a0, b1 = a1, b2 = a2;
        if (ch < 9) {
            int nt = DIR ? (96 - ch * 12) : (12 + ch * 12);
            b0 = *reinterpret_cast<const float4*>(xp + nt);
            b1 = *reinterpret_cast<const float4*>(xp + nt + 4);
            b2 = *reinterpret_cast<const float4*>(xp + nt + 8);
        }
        float zz[12] = {a0.x, a0.y, a0.z, a0.w, a1.x, a1.y, a1.z, a1.w, a2.x, a2.y, a2.z, a2.w};
        int tbase = DIR ? (108 - ch * 12) : (ch * 12);
#pragma unroll
        for (int ii = 0; ii < 12; ++ii) {
            int idx = DIR ? (11 - ii) : ii;
            float z = zz[idx] + ((w.x * h0 + w.y * h1) + (w.z * h2 + w.w * h3));
            float zi = __shfl(z, k, 16);
            float zf = __shfl(z, k + 4, 16);
            float zg = __shfl(z, k + 8, 16);
            float zo = __shfl(z, k + 12, 16);
            float ig = fsigm(zi), fg = fsigm(zf), gg = ftanh(zg), og = fsigm(zo);
            cst = fg * cst + ig * gg;
            float hn = og * ftanh(cst);
            h0 = __shfl(hn, 0, 16); h1 = __shfl(hn, 1, 16);
            h2 = __shfl(hn, 2, 16); h3 = __shfl(hn, 3, 16);
            if (j < 4) newF[((size_t)b * 120 + tbase + idx) * 8 + DIR * 4 + j] = hn;
        }
        a0 = b0; a1 = b1; a2 = b2;
    }
}

__global__ __launch_bounds__(64)
void lstm_seq2(const float* __restrict__ xWf, const float* __restrict__ xWb,
               const float* __restrict__ Whhf, const float* __restrict__ Whhb,
               float* __restrict__ newF, int B)
{
    int sub = threadIdx.x >> 4;
    int chain = blockIdx.x * 4 + sub;
    if (chain >= 2 * B) return;
    int d = chain / B;
    int b = chain - d * B;
    if (d == 0) lstm_chain<0>(xWf, Whhf, newF, b);
    else        lstm_chain<1>(xWb, Whhb, newF, b);
}

// ---------------- GraphConv combine + L1 norm
__global__ __launch_bounds__(192)
void gc_combine(const float* __restrict__ stackFT, const float* __restrict__ hw,
                const int* __restrict__ rowstart, const int* __restrict__ csrc,
                const float* __restrict__ rs_in,
                const float* __restrict__ b_gc, float* __restrict__ h, int n)
{
    int v = blockIdx.x;
    int f = threadIdx.x;
    int s0 = rowstart[v], s1 = rowstart[v + 1];
    float s = 0.f;
    int u = (s0 < s1) ? csrc[s0] : 0;
    for (int i = s0; i < s1; ++i) {
        int un = (i + 1 < s1) ? csrc[i + 1] : 0;
        s += hw[(size_t)u * 192 + f];
        u = un;
    }
    float val = 0.5f * (stackFT[(size_t)v * 192 + f] + s * rs_in[v] + b_gc[f]);
    __shared__ float red[192];
    red[f] = fabsf(val);
    __syncthreads();
    if (f < 64) red[f] = red[f] + red[f + 64] + red[f + 128];
    __syncthreads();
    if (f < 64) {
        float r = red[f];
        for (int o = 32; o; o >>= 1) r += __shfl_down(r, o, 64);
        if (f == 0) red[0] = r;
    }
    __syncthreads();
    float denom = fmaxf(red[0], 1e-12f);
    h[(size_t)v * 192 + f] = val / denom;
}

// ---------------- GATv2 edge pass (CSR, one block per dst node), H=16 heads
// fs at col 0, fd at col HF, (fused) res at col 2*HF of fs_base with row stride ld
template<int F, bool FUSED>
__global__ void gat_edge(const float* __restrict__ fs_base, int ld,
                         const float* __restrict__ attn,
                         const int* __restrict__ rowstart, const int* __restrict__ csrc,
                         float* __restrict__ outp, float* __restrict__ den, int n)
{
    constexpr int HF = 16 * F;
    int v = blockIdx.x;
    int t = threadIdx.x;
    float fdv = fs_base[(size_t)v * ld + HF + t];
    float at = attn[t];
    float acc = 0.f, dn = 0.f;
    int s0 = rowstart[v], s1 = rowstart[v + 1];
    int u = (s0 < s1) ? csrc[s0] : 0;
    for (int i = s0; i < s1; ++i) {
        int un = (i + 1 < s1) ? csrc[i + 1] : 0;
        float sv = fs_base[(size_t)u * ld + t];
        float w = sv + fdv;
        w = (w > 0.f) ? w : 0.2f * w;
        float p = w * at;
#pragma unroll
        for (int o = F >> 1; o; o >>= 1) p += __shfl_xor(p, o, F);
        float ex = __expf(p);
        acc += ex * sv;
        dn += ex;
        u = un;
    }
    if (FUSED) {
        float r = fs_base[(size_t)v * ld + 2 * HF + t];
        float o = (dn > 0.f) ? __fdividef(acc, dn) : 0.f;
        outp[(size_t)v * HF + t] = fmaxf(o + r, 0.f);
    } else {
        outp[(size_t)v * HF + t] = acc;
        if ((t & (F - 1)) == 0) den[(size_t)v * 16 + t / F] = dn;
    }
}

__global__ void gat_fin(const float* __restrict__ den, const float* __restrict__ res,
                        float* __restrict__ num, int HF, int F, int total)
{
    int i = blockIdx.x * blockDim.x + threadIdx.x;
    if (i >= total) return;
    int v = i / HF, t = i - v * HF, h = t / F;
    float d = den[(size_t)v * 16 + h];
    float o = (d > 0.f) ? num[i] / d : 0.f;
    num[i] = fmaxf(o + res[i], 0.f);
}

// ---------------- final classifier
__global__ void final_lin(const float* __restrict__ h1, const float* __restrict__ newF,
                          const float* __restrict__ h3, const float* __restrict__ W,
                          const float* __restrict__ bias, float* __restrict__ out, int n)
{
    int gid = blockIdx.x * blockDim.x + threadIdx.x;
    if (gid >= n * 6) return;
    int v = gid / 6, o = gid - v * 6;
    float s = bias[o];
    const float* a = h1 + (size_t)v * 64;
#pragma unroll 8
    for (int r = 0; r < 64; ++r) s += a[r] * W[r * 6 + o];
    const float* b = newF + (size_t)v * 8;
#pragma unroll
    for (int r = 0; r < 8; ++r) s += b[r] * W[(64 + r) * 6 + o];
    const float* c = h3 + (size_t)v * 64;
#pragma unroll 8
    for (int r = 0; r < 64; ++r) s += c[r] * W[(72 + r) * 6 + o];
    out[gid] = s;
}

// ----------------------------------------------------------------------------
extern "C" void kernel_launch(void* const* d_in, const int* in_sizes, int n_in,
                              void* d_out, int out_size, void* d_ws, size_t ws_size,
                              hipStream_t stream)
{
    const float* text   = (const float*)d_in[0];
    const float* audio  = (const float*)d_in[1];
    const float* vision = (const float*)d_in[2];
    const int*   esrc   = (const int*)d_in[3];
    const int*   edst   = (const int*)d_in[4];
    const float* W_audio = (const float*)d_in[5];  const float* b_audio = (const float*)d_in[6];
    const float* W_vision= (const float*)d_in[7];  const float* b_vision= (const float*)d_in[8];
    const float* W_text  = (const float*)d_in[9];  const float* b_text  = (const float*)d_in[10];
    const float* Wih_f = (const float*)d_in[11]; const float* Whh_f = (const float*)d_in[12];
    const float* bih_f = (const float*)d_in[13]; const float* bhh_f = (const float*)d_in[14];
    const float* Wih_b = (const float*)d_in[15]; const float* Whh_b = (const float*)d_in[16];
    const float* bih_b = (const float*)d_in[17]; const float* bhh_b = (const float*)d_in[18];
    const float* W_gc  = (const float*)d_in[19]; const float* b_gc  = (const float*)d_in[20];
    const float* Wsrc2 = (const float*)d_in[21]; const float* bsrc2 = (const float*)d_in[22];
    const float* Wdst2 = (const float*)d_in[23]; const float* bdst2 = (const float*)d_in[24];
    const float* attn2 = (const float*)d_in[25]; const float* Wres2 = (const float*)d_in[26];
    const float* Wsrc0 = (const float*)d_in[27]; const float* bsrc0 = (const float*)d_in[28];
    const float* Wdst0 = (const float*)d_in[29]; const float* bdst0 = (const float*)d_in[30];
    const float* attn0 = (const float*)d_in[31]; const float* Wres0 = (const float*)d_in[32];
    const float* Wsrc1 = (const float*)d_in[33]; const float* bsrc1 = (const float*)d_in[34];
    const float* Wdst1 = (const float*)d_in[35]; const float* bdst1 = (const float*)d_in[36];
    const float* attn1 = (const float*)d_in[37]; const float* Wres1 = (const float*)d_in[38];
    const float* W_lin = (const float*)d_in[39]; const float* b_lin = (const float*)d_in[40];
    float* out = (float*)d_out;

    const int n = in_sizes[0] / 1024;   // 12000
    const int E = in_sizes[3];          // 192000
    const int B = n / 120;              // 100

    // ---- workspace carve (256B aligned) — total ~102 MB, same as round 1
    char* p = (char*)d_ws;
    auto alloc_f = [&](size_t cnt) { float* r = (float*)p; p += ((cnt * 4 + 255) / 256) * 256; return r; };
    auto alloc_i = [&](size_t cnt) { int* r = (int*)p; p += ((cnt * 4 + 255) / 256) * 256; return r; };
    float* stackFT = alloc_f((size_t)n * 192);   // reused as gat2 packed out [n,192]
    float* hbuf    = alloc_f((size_t)n * 192);
    float* xWf     = alloc_f((size_t)n * 16);    // transposed [B,16,120]
    float* xWb     = alloc_f((size_t)n * 16);
    float* newF    = alloc_f((size_t)n * 8);
    float* big0    = alloc_f((size_t)n * 512);   // big0..big2 contiguous (73.7 MB)
    float* big1    = alloc_f((size_t)n * 512);
    float* big2    = alloc_f((size_t)n * 512);
    float* den     = alloc_f((size_t)n * 16);
    float* h3      = alloc_f((size_t)n * 64);
    float* h1s     = alloc_f((size_t)n * 64);    // first 200 KB doubles as packed-W scratch pre-gat1-edge
    float* rs_out  = alloc_f(n);
    float* rs_in   = alloc_f(n);
    int* zero_base = alloc_i((size_t)3 * n);     // degout, degin, cursor
    int* degout = zero_base;
    int* degin  = zero_base + n;
    int* cursor = zero_base + 2 * n;
    int* rowstart = alloc_i((size_t)n + 1);
    int* perm     = alloc_i((size_t)E);          // becomes csr_src after gather
    if ((size_t)(p - (char*)d_ws) > ws_size) return;

    float* pw = h1s;                 // packed weights scratch (<= 192*1024 floats, fits in h1s)
    float* pb = h1s + 200704;        // packed bias scratch

    (void)big1;

    // ---- graph preprocessing (CSR by dst, src gathered in-place)
    hipMemsetAsync(zero_base, 0, (size_t)3 * n * 4, stream);
    deg_kernel<<<(E + 255) / 256, 256, 0, stream>>>(esrc, edst, degout, degin, E);
    scan_kernel<<<1, 1024, 0, stream>>>(degin, rowstart, n);
    perm_kernel<<<(E + 255) / 256, 256, 0, stream>>>(edst, rowstart, cursor, perm, E);
    gather_src_kernel<<<(E + 255) / 256, 256, 0, stream>>>(esrc, perm, E);
    rs_kernel<<<(n + 255) / 256, 256, 0, stream>>>(degout, degin, rs_out, rs_in, n);
    const int* csrc = perm;

    auto gemm64 = [&](const float* A, const float* Bm, const float* bias, const float* rsc,
                      float* C, int M, int Nb, int K, int ldc) {
        dim3 grid((M + 63) / 64, Nb / 64);
        gemm_kernel<64, 4><<<grid, 256, 0, stream>>>(A, Bm, bias, rsc, C, M, Nb, K, ldc, 0);
    };
    auto gemm128 = [&](const float* A, const float* Bm, const float* bias, const float* rsc,
                       float* C, int M, int Nb, int K, int ldc) {
        dim3 grid((M + 127) / 128, Nb / 64);
        gemm_kernel<128, 8><<<grid, 256, 0, stream>>>(A, Bm, bias, rsc, C, M, Nb, K, ldc, 0);
    };

    // ---- modality encoders -> stackFT [n,192] (one fused launch, 564 blocks)
    {
        dim3 grid((n + 63) / 64, 1, 3);
        enc3_kernel<<<grid, 256, 0, stream>>>(text, audio, vision, W_text, W_audio, W_vision,
                                              b_text, b_audio, b_vision, stackFT, n);
    }

    // ---- BiLSTM
    lstm_pre<<<(n * 32 + 255) / 256, 256, 0, stream>>>(stackFT, Wih_f, Wih_b,
                                                       bih_f, bhh_f, bih_b, bhh_b, xWf, xWb, n);
    lstm_seq2<<<(2 * B + 3) / 4, 64, 0, stream>>>(xWf, xWb, Whh_f, Whh_b, newF, B);

    // ---- GraphConv imputation + L1 norm -> hbuf [n,192]
    gemm64(stackFT, W_gc, nullptr, rs_out, big0, n, 192, 192, 192);
    gc_combine<<<n, 192, 0, stream>>>(stackFT, big0, rowstart, csrc, rs_in, b_gc, hbuf, n);

    // ---- gat2: pack Wsrc|Wdst|Wres (192->192), one GEMM, fused edge+fin -> h3 [n,64]
    pack3_kernel<<<(192 * 192 + 255) / 256, 256, 0, stream>>>(Wsrc2, Wdst2, Wres2, bsrc2, bdst2, pw, pb, 192, 64);
    gemm64(hbuf, pw, pb, nullptr, stackFT, n, 192, 192, 192);      // stackFT reused as [n,192]
    gat_edge<4, true><<<n, 64, 0, stream>>>(stackFT, 192, attn2, rowstart, csrc, h3, nullptr, n);

    // ---- gat0: pack Wsrc|Wdst (192->1024), GEMM -> big0:[n,1024]; edge -> big2; res GEMM -> big0; fin
    pack2_kernel<<<(192 * 1024 + 255) / 256, 256, 0, stream>>>(Wsrc0, Wdst0, bsrc0, bdst0, pw, pb, 192, 512);
    gemm128(hbuf, pw, pb, nullptr, big0, n, 1024, 192, 1024);
    gat_edge<32, false><<<n, 512, 0, stream>>>(big0, 1024, attn0, rowstart, csrc, big2, den, n);
    gemm128(hbuf, Wres0, nullptr, nullptr, big0, n, 512, 192, 512);
    gat_fin<<<(n * 512 + 255) / 256, 256, 0, stream>>>(den, big0, big2, 512, 32, n * 512);

    // ---- gat1: pack Wsrc|Wdst|Wres (512->192), GEMM -> big0:[n,192], fused edge+fin -> h1s
    pack3_kernel<<<(512 * 192 + 255) / 256, 256, 0, stream>>>(Wsrc1, Wdst1, Wres1, bsrc1, bdst1, pw, pb, 512, 64);
    gemm64(big2, pw, pb, nullptr, big0, n, 192, 512, 192);
    gat_edge<4, true><<<n, 64, 0, stream>>>(big0, 192, attn1, rowstart, csrc, h1s, nullptr, n);

    // ---- final classifier
    final_lin<<<(n * 6 + 255) / 256, 256, 0, stream>>>(h1s, newF, h3, W_lin, b_lin, out, n);
}

// Round 3
// 515.093 us; speedup vs baseline: 2.3321x; 1.3233x over previous
//
#include <hip/hip_runtime.h>

typedef __attribute__((ext_vector_type(8))) short short8;
typedef __attribute__((ext_vector_type(4))) float f32x4;

__device__ __forceinline__ unsigned short f2bf(float f) {
    unsigned u = __float_as_uint(f);
    u += 0x7FFFu + ((u >> 16) & 1u);
    return (unsigned short)(u >> 16);
}

// ---------------- bf16 MFMA GEMM: C[M,Nb] = A[M,K]@B[K,Nb] (+bias)(*rowscale), f32 in/out
// BM=128, BN=64, BK=32; 256 thr = 4 waves; wave w: rows w*32..+31 (2 m-frags), 4 n-frags
__global__ __launch_bounds__(256)
void mfma_gemm(const float* __restrict__ A, const float* __restrict__ B,
               const float* __restrict__ bias, const float* __restrict__ rowscale,
               float* __restrict__ C, int M, int Nb, int K, int ldc, int ccol)
{
    __shared__ alignas(16) unsigned short Al[4][128][8];  // [kgrp][m][e]
    __shared__ alignas(16) unsigned short Bl[4][64][8];   // [kgrp][c][e]
    const int t = threadIdx.x;
    const int w = t >> 6, l = t & 63;
    const int row0 = blockIdx.x * 128;
    const int col0 = blockIdx.y * 64;
    f32x4 acc[2][4] = {};
    for (int k0 = 0; k0 < K; k0 += 32) {
        // stage A: 128 rows x 8 float4s = 1024, 4 per thread
#pragma unroll
        for (int s = 0; s < 4; ++s) {
            int idx = s * 256 + t;
            int m = idx >> 3, kq = idx & 7;
            int gm = row0 + m;
            float4 av = make_float4(0.f, 0.f, 0.f, 0.f);
            if (gm < M) av = *reinterpret_cast<const float4*>(A + (size_t)gm * K + k0 + kq * 4);
            ushort4 pk = make_ushort4(f2bf(av.x), f2bf(av.y), f2bf(av.z), f2bf(av.w));
            *reinterpret_cast<ushort4*>(&Al[kq >> 1][m][(kq & 1) * 4]) = pk;
        }
        // stage B: 32k x 64n; threads 0..127 each transpose a 4k x 4n block
        if (t < 128) {
            int kb = (t >> 4) * 4;            // 0,4,...,28
            int cb = (t & 15) * 4;
            const float* bp = B + (size_t)(k0 + kb) * Nb + col0 + cb;
            float4 r0 = *reinterpret_cast<const float4*>(bp);
            float4 r1 = *reinterpret_cast<const float4*>(bp + Nb);
            float4 r2 = *reinterpret_cast<const float4*>(bp + 2 * (size_t)Nb);
            float4 r3 = *reinterpret_cast<const float4*>(bp + 3 * (size_t)Nb);
            int g = kb >> 3, hh = (kb >> 2) & 1;
            float c0[4] = {r0.x, r1.x, r2.x, r3.x};
            float c1[4] = {r0.y, r1.y, r2.y, r3.y};
            float c2[4] = {r0.z, r1.z, r2.z, r3.z};
            float c3[4] = {r0.w, r1.w, r2.w, r3.w};
            *reinterpret_cast<ushort4*>(&Bl[g][cb + 0][hh * 4]) = make_ushort4(f2bf(c0[0]), f2bf(c0[1]), f2bf(c0[2]), f2bf(c0[3]));
            *reinterpret_cast<ushort4*>(&Bl[g][cb + 1][hh * 4]) = make_ushort4(f2bf(c1[0]), f2bf(c1[1]), f2bf(c1[2]), f2bf(c1[3]));
            *reinterpret_cast<ushort4*>(&Bl[g][cb + 2][hh * 4]) = make_ushort4(f2bf(c2[0]), f2bf(c2[1]), f2bf(c2[2]), f2bf(c2[3]));
            *reinterpret_cast<ushort4*>(&Bl[g][cb + 3][hh * 4]) = make_ushort4(f2bf(c3[0]), f2bf(c3[1]), f2bf(c3[2]), f2bf(c3[3]));
        }
        __syncthreads();
        int kg = l >> 4, r16 = l & 15;
        short8 a0 = *reinterpret_cast<const short8*>(&Al[kg][w * 32 + r16][0]);
        short8 a1 = *reinterpret_cast<const short8*>(&Al[kg][w * 32 + 16 + r16][0]);
        short8 b0 = *reinterpret_cast<const short8*>(&Bl[kg][r16][0]);
        short8 b1 = *reinterpret_cast<const short8*>(&Bl[kg][16 + r16][0]);
        short8 b2 = *reinterpret_cast<const short8*>(&Bl[kg][32 + r16][0]);
        short8 b3 = *reinterpret_cast<const short8*>(&Bl[kg][48 + r16][0]);
        acc[0][0] = __builtin_amdgcn_mfma_f32_16x16x32_bf16(a0, b0, acc[0][0], 0, 0, 0);
        acc[0][1] = __builtin_amdgcn_mfma_f32_16x16x32_bf16(a0, b1, acc[0][1], 0, 0, 0);
        acc[0][2] = __builtin_amdgcn_mfma_f32_16x16x32_bf16(a0, b2, acc[0][2], 0, 0, 0);
        acc[0][3] = __builtin_amdgcn_mfma_f32_16x16x32_bf16(a0, b3, acc[0][3], 0, 0, 0);
        acc[1][0] = __builtin_amdgcn_mfma_f32_16x16x32_bf16(a1, b0, acc[1][0], 0, 0, 0);
        acc[1][1] = __builtin_amdgcn_mfma_f32_16x16x32_bf16(a1, b1, acc[1][1], 0, 0, 0);
        acc[1][2] = __builtin_amdgcn_mfma_f32_16x16x32_bf16(a1, b2, acc[1][2], 0, 0, 0);
        acc[1][3] = __builtin_amdgcn_mfma_f32_16x16x32_bf16(a1, b3, acc[1][3], 0, 0, 0);
        __syncthreads();
    }
#pragma unroll
    for (int mi = 0; mi < 2; ++mi)
#pragma unroll
        for (int ni = 0; ni < 4; ++ni) {
            int col = col0 + ni * 16 + (l & 15);
            float bv = bias ? bias[col] : 0.f;
#pragma unroll
            for (int r = 0; r < 4; ++r) {
                int gm = row0 + w * 32 + mi * 16 + (l >> 4) * 4 + r;
                if (gm < M) {
                    float rs = rowscale ? rowscale[gm] : 1.f;
                    C[(size_t)gm * ldc + ccol + col] = (acc[mi][ni][r] + bv) * rs;
                }
            }
        }
}

// ---------------- f32 tiled GEMM body (kept for the memory-bound encoder GEMM)
template<int BM, int TM>
__device__ __forceinline__ void gemm_body(const float* __restrict__ A, const float* __restrict__ B,
                                          const float* __restrict__ bias,
                                          float* __restrict__ C, int M, int Nb, int K, int ldc, int ccol,
                                          int bx, int by)
{
    __shared__ float As[16][BM + 4];
    __shared__ float Bs[16][64];
    const int t = threadIdx.x;
    const int tx = t & 15, ty = t >> 4;
    const int row0 = bx * BM;
    const int col0 = by * 64;
    float acc[TM][4] = {};
    for (int k0 = 0; k0 < K; k0 += 16) {
#pragma unroll
        for (int s = 0; s < BM / 64; ++s) {
            int idx4 = t + s * 256;
            int m = idx4 >> 2, k4 = (idx4 & 3) << 2;
            int gm = row0 + m;
            float4 av = make_float4(0.f, 0.f, 0.f, 0.f);
            if (gm < M) av = *reinterpret_cast<const float4*>(A + (size_t)gm * K + k0 + k4);
            As[k4 + 0][m] = av.x; As[k4 + 1][m] = av.y; As[k4 + 2][m] = av.z; As[k4 + 3][m] = av.w;
        }
        {
            int kk = t >> 4, n4 = (t & 15) << 2;
            float4 bv = *reinterpret_cast<const float4*>(B + (size_t)(k0 + kk) * Nb + col0 + n4);
            *reinterpret_cast<float4*>(&Bs[kk][n4]) = bv;
        }
        __syncthreads();
#pragma unroll
        for (int kk = 0; kk < 16; ++kk) {
            float4 bv = *reinterpret_cast<const float4*>(&Bs[kk][tx * 4]);
            float av[TM];
#pragma unroll
            for (int i = 0; i < TM / 4; ++i) {
                float4 a4 = *reinterpret_cast<const float4*>(&As[kk][ty * TM + i * 4]);
                av[i * 4 + 0] = a4.x; av[i * 4 + 1] = a4.y; av[i * 4 + 2] = a4.z; av[i * 4 + 3] = a4.w;
            }
#pragma unroll
            for (int i = 0; i < TM; ++i) {
                acc[i][0] += av[i] * bv.x; acc[i][1] += av[i] * bv.y;
                acc[i][2] += av[i] * bv.z; acc[i][3] += av[i] * bv.w;
            }
        }
        __syncthreads();
    }
#pragma unroll
    for (int i = 0; i < TM; ++i) {
        int gm = row0 + ty * TM + i;
        if (gm >= M) break;
        float4 v = make_float4(acc[i][0], acc[i][1], acc[i][2], acc[i][3]);
        if (bias) {
            const float* bp = bias + col0 + tx * 4;
            v.x += bp[0]; v.y += bp[1]; v.z += bp[2]; v.w += bp[3];
        }
        *reinterpret_cast<float4*>(C + (size_t)gm * ldc + ccol + col0 + tx * 4) = v;
    }
}

__global__ __launch_bounds__(256)
void enc3_kernel(const float* __restrict__ text, const float* __restrict__ audio, const float* __restrict__ vision,
                 const float* __restrict__ Wt, const float* __restrict__ Wa, const float* __restrict__ Wv,
                 const float* __restrict__ bt, const float* __restrict__ ba, const float* __restrict__ bv,
                 float* __restrict__ C, int M)
{
    int z = blockIdx.z;
    const float* A  = (z == 0) ? text : (z == 1) ? audio : vision;
    const float* Bm = (z == 0) ? Wt   : (z == 1) ? Wa    : Wv;
    const float* bb = (z == 0) ? bt   : (z == 1) ? ba    : bv;
    int K = (z == 1) ? 512 : 1024;
    gemm_body<64, 4>(A, Bm, bb, C, M, 64, K, 192, z * 64, blockIdx.x, 0);
}

// ---------------- weight packing
__global__ void pack3_kernel(const float* __restrict__ W0, const float* __restrict__ W1, const float* __restrict__ W2,
                             const float* __restrict__ b0, const float* __restrict__ b1,
                             float* __restrict__ Wp, float* __restrict__ bp, int K, int O)
{
    int gid = blockIdx.x * blockDim.x + threadIdx.x;
    int O3 = 3 * O;
    if (gid < O3) bp[gid] = (gid < O) ? b0[gid] : (gid < 2 * O) ? b1[gid - O] : 0.f;
    if (gid >= K * O3) return;
    int k = gid / O3, c = gid - k * O3;
    float v = (c < O) ? W0[k * O + c] : (c < 2 * O) ? W1[k * O + c - O] : W2[k * O + c - 2 * O];
    Wp[gid] = v;
}

__global__ void pack2_kernel(const float* __restrict__ W0, const float* __restrict__ W1,
                             const float* __restrict__ b0, const float* __restrict__ b1,
                             float* __restrict__ Wp, float* __restrict__ bp, int K, int O)
{
    int gid = blockIdx.x * blockDim.x + threadIdx.x;
    int O2 = 2 * O;
    if (gid < O2) bp[gid] = (gid < O) ? b0[gid] : b1[gid - O];
    if (gid >= K * O2) return;
    int k = gid / O2, c = gid - k * O2;
    Wp[gid] = (c < O) ? W0[k * O + c] : W1[k * O + c - O];
}

// ---------------- graph preprocessing
__global__ void deg_kernel(const int* __restrict__ src, const int* __restrict__ dst,
                           int* degout, int* degin, int E)
{
    int e = blockIdx.x * blockDim.x + threadIdx.x;
    if (e < E) {
        atomicAdd(&degout[src[e]], 1);
        atomicAdd(&degin[dst[e]], 1);
    }
}

__global__ __launch_bounds__(1024)
void scan_kernel(const int* __restrict__ degin, int* __restrict__ rowstart, int n)
{
    __shared__ int part[1024];
    int t = threadIdx.x;
    int chunk = (n + 1023) / 1024;
    int s = 0;
    for (int i = 0; i < chunk; ++i) {
        int idx = t * chunk + i;
        if (idx < n) s += degin[idx];
    }
    part[t] = s;
    __syncthreads();
    for (int o = 1; o < 1024; o <<= 1) {
        int v = (t >= o) ? part[t - o] : 0;
        __syncthreads();
        part[t] += v;
        __syncthreads();
    }
    int run = (t > 0) ? part[t - 1] : 0;
    for (int i = 0; i < chunk; ++i) {
        int idx = t * chunk + i;
        if (idx < n) { rowstart[idx] = run; run += degin[idx]; }
    }
    if (t == 1023) rowstart[n] = part[1023];
}

__global__ void perm_kernel(const int* __restrict__ dst, const int* __restrict__ rowstart,
                            int* cursor, int* __restrict__ perm, int E)
{
    int e = blockIdx.x * blockDim.x + threadIdx.x;
    if (e < E) {
        int v = dst[e];
        int p = atomicAdd(&cursor[v], 1);
        perm[rowstart[v] + p] = e;
    }
}

__global__ void gather_src_kernel(const int* __restrict__ esrc, int* perm, int E)
{
    int i = blockIdx.x * blockDim.x + threadIdx.x;
    if (i < E) perm[i] = esrc[perm[i]];
}

__global__ void rs_kernel(const int* degout, const int* degin, float* rso, float* rsi, int n)
{
    int i = blockIdx.x * blockDim.x + threadIdx.x;
    if (i < n) {
        rso[i] = rsqrtf((float)max(degout[i], 1));
        rsi[i] = rsqrtf((float)max(degin[i], 1));
    }
}

// ---------------- LSTM
__global__ void lstm_pre(const float* __restrict__ x, const float* __restrict__ Wf,
                         const float* __restrict__ Wb,
                         const float* bf1, const float* bf2, const float* bb1, const float* bb2,
                         float* __restrict__ xWf, float* __restrict__ xWb, int n)
{
    int gid = blockIdx.x * blockDim.x + threadIdx.x;
    if (gid >= n * 32) return;
    int nn = gid >> 5, r = gid & 31, d = r >> 4, j = r & 15;
    const float* W = (d ? Wb : Wf) + j * 192;
    const float* xr = x + (size_t)nn * 192;
    float s = 0.f;
#pragma unroll 4
    for (int k = 0; k < 192; k += 4) {
        float4 xv = *reinterpret_cast<const float4*>(xr + k);
        float4 wv = *reinterpret_cast<const float4*>(W + k);
        s += xv.x * wv.x + xv.y * wv.y + xv.z * wv.z + xv.w * wv.w;
    }
    s += d ? (bb1[j] + bb2[j]) : (bf1[j] + bf2[j]);
    int b = nn / 120, tt = nn - b * 120;
    (d ? xWb : xWf)[((size_t)b * 16 + j) * 120 + tt] = s;
}

__device__ __forceinline__ float fsigm(float x) { return __fdividef(1.f, 1.f + __expf(-x)); }
__device__ __forceinline__ float ftanh(float x) { return 1.f - __fdividef(2.f, __expf(2.f * x) + 1.f); }

template<int DIR>
__device__ void lstm_chain(const float* __restrict__ xw, const float* __restrict__ whh,
                           float* __restrict__ newF, int b)
{
    int j = threadIdx.x & 15;
    int k = j & 3;
    float4 w = *reinterpret_cast<const float4*>(whh + j * 4);
    const float* xp = xw + ((size_t)b * 16 + j) * 120;
    float h0 = 0.f, h1 = 0.f, h2 = 0.f, h3 = 0.f, cst = 0.f;
    int tb0 = DIR ? 108 : 0;
    float4 a0 = *reinterpret_cast<const float4*>(xp + tb0);
    float4 a1 = *reinterpret_cast<const float4*>(xp + tb0 + 4);
    float4 a2 = *reinterpret_cast<const float4*>(xp + tb0 + 8);
    for (int ch = 0; ch < 10; ++ch) {
        float4 b0 = a0, b1 = a1, b2 = a2;
        if (ch < 9) {
            int nt = DIR ? (96 - ch * 12) : (12 + ch * 12);
            b0 = *reinterpret_cast<const float4*>(xp + nt);
            b1 = *reinterpret_cast<const float4*>(xp + nt + 4);
            b2 = *reinterpret_cast<const float4*>(xp + nt + 8);
        }
        float zz[12] = {a0.x, a0.y, a0.z, a0.w, a1.x, a1.y, a1.z, a1.w, a2.x, a2.y, a2.z, a2.w};
        int tbase = DIR ? (108 - ch * 12) : (ch * 12);
#pragma unroll
        for (int ii = 0; ii < 12; ++ii) {
            int idx = DIR ? (11 - ii) : ii;
            float z = zz[idx] + ((w.x * h0 + w.y * h1) + (w.z * h2 + w.w * h3));
            float zi = __shfl(z, k, 16);
            float zf = __shfl(z, k + 4, 16);
            float zg = __shfl(z, k + 8, 16);
            float zo = __shfl(z, k + 12, 16);
            float ig = fsigm(zi), fg = fsigm(zf), gg = ftanh(zg), og = fsigm(zo);
            cst = fg * cst + ig * gg;
            float hn = og * ftanh(cst);
            h0 = __shfl(hn, 0, 16); h1 = __shfl(hn, 1, 16);
            h2 = __shfl(hn, 2, 16); h3 = __shfl(hn, 3, 16);
            if (j < 4) newF[((size_t)b * 120 + tbase + idx) * 8 + DIR * 4 + j] = hn;
        }
        a0 = b0; a1 = b1; a2 = b2;
    }
}

__global__ __launch_bounds__(64)
void lstm_seq2(const float* __restrict__ xWf, const float* __restrict__ xWb,
               const float* __restrict__ Whhf, const float* __restrict__ Whhb,
               float* __restrict__ newF, int B)
{
    int sub = threadIdx.x >> 4;
    int chain = blockIdx.x * 4 + sub;
    if (chain >= 2 * B) return;
    int d = chain / B;
    int b = chain - d * B;
    if (d == 0) lstm_chain<0>(xWf, Whhf, newF, b);
    else        lstm_chain<1>(xWb, Whhb, newF, b);
}

// ---------------- GraphConv combine + L1 norm: one wave per node, 3 feats/lane
__global__ __launch_bounds__(256)
void gc_combine2(const float* __restrict__ stackFT, const float* __restrict__ hw,
                 const int* __restrict__ rowstart, const int* __restrict__ csrc,
                 const float* __restrict__ rs_in,
                 const float* __restrict__ b_gc, float* __restrict__ h, int n)
{
    int v = blockIdx.x * 4 + (threadIdx.x >> 6);
    int l = threadIdx.x & 63;
    if (v >= n) return;
    int s0 = rowstart[v], s1 = rowstart[v + 1];
    float sum0 = 0.f, sum1 = 0.f, sum2 = 0.f;
    int u = (s0 < s1) ? csrc[s0] : 0;
    for (int i = s0; i < s1; ++i) {
        int un = (i + 1 < s1) ? csrc[i + 1] : 0;
        const float* hr = hw + (size_t)u * 192 + l;
        float p0 = hr[0], p1 = hr[64], p2 = hr[128];
        sum0 += p0; sum1 += p1; sum2 += p2;
        u = un;
    }
    float ri = rs_in[v];
    const float* sf = stackFT + (size_t)v * 192 + l;
    float v0 = 0.5f * (sf[0]   + sum0 * ri + b_gc[l]);
    float v1 = 0.5f * (sf[64]  + sum1 * ri + b_gc[l + 64]);
    float v2 = 0.5f * (sf[128] + sum2 * ri + b_gc[l + 128]);
    float r = fabsf(v0) + fabsf(v1) + fabsf(v2);
#pragma unroll
    for (int o = 32; o; o >>= 1) r += __shfl_xor(r, o);
    float inv = __fdividef(1.f, fmaxf(r, 1e-12f));
    float* hp = h + (size_t)v * 192 + l;
    hp[0] = v0 * inv; hp[64] = v1 * inv; hp[128] = v2 * inv;
}

// ---------------- GATv2 F=4 (HF=64): 16 lanes/node, one float4 = one head per lane, fused epilogue
__global__ __launch_bounds__(256)
void gat_edge4(const float* __restrict__ base, int ld,   // fs|fd|res packed, row stride ld
               const float* __restrict__ attn,           // [16][4]
               const int* __restrict__ rowstart, const int* __restrict__ csrc,
               float* __restrict__ outp, int n)
{
    int v = blockIdx.x * 16 + (threadIdx.x >> 4);
    int l = threadIdx.x & 15;      // head
    if (v >= n) return;
    float4 at  = *reinterpret_cast<const float4*>(attn + l * 4);
    float4 fdv = *reinterpret_cast<const float4*>(base + (size_t)v * ld + 64 + l * 4);
    float4 acc = make_float4(0.f, 0.f, 0.f, 0.f);
    float dn = 0.f;
    int s0 = rowstart[v], s1 = rowstart[v + 1];
    int u = (s0 < s1) ? csrc[s0] : 0;
    float4 sv = (s0 < s1) ? *reinterpret_cast<const float4*>(base + (size_t)u * ld + l * 4)
                          : make_float4(0.f, 0.f, 0.f, 0.f);
    for (int i = s0; i < s1; ++i) {
        int un = (i + 1 < s1) ? csrc[i + 1] : 0;
        float4 svn = (i + 1 < s1) ? *reinterpret_cast<const float4*>(base + (size_t)un * ld + l * 4)
                                  : make_float4(0.f, 0.f, 0.f, 0.f);
        float ex_, ey, ez, ew;
        ex_ = sv.x + fdv.x; ex_ = (ex_ > 0.f) ? ex_ : 0.2f * ex_;
        ey  = sv.y + fdv.y; ey  = (ey  > 0.f) ? ey  : 0.2f * ey;
        ez  = sv.z + fdv.z; ez  = (ez  > 0.f) ? ez  : 0.2f * ez;
        ew  = sv.w + fdv.w; ew  = (ew  > 0.f) ? ew  : 0.2f * ew;
        float p = ex_ * at.x + ey * at.y + ez * at.z + ew * at.w;
        float ex = __expf(p);
        acc.x += ex * sv.x; acc.y += ex * sv.y; acc.z += ex * sv.z; acc.w += ex * sv.w;
        dn += ex;
        sv = svn; u = un;
    }
    float4 r = *reinterpret_cast<const float4*>(base + (size_t)v * ld + 128 + l * 4);
    float inv = (dn > 0.f) ? __fdividef(1.f, dn) : 0.f;
    float4 o;
    o.x = fmaxf(acc.x * inv + r.x, 0.f);
    o.y = fmaxf(acc.y * inv + r.y, 0.f);
    o.z = fmaxf(acc.z * inv + r.z, 0.f);
    o.w = fmaxf(acc.w * inv + r.w, 0.f);
    *reinterpret_cast<float4*>(outp + (size_t)v * 64 + l * 4) = o;
}

// ---------------- GATv2 F=32 (HF=512): 128 lanes/node (float4 each), 8-lane head reduce
__global__ __launch_bounds__(256)
void gat_edge32(const float* __restrict__ base,          // [n,1024] fs|fd
                const float* __restrict__ attn,          // [16][32]
                const int* __restrict__ rowstart, const int* __restrict__ csrc,
                float* __restrict__ num, float* __restrict__ den, int n)
{
    int v = blockIdx.x * 2 + (threadIdx.x >> 7);
    int l = threadIdx.x & 127;
    if (v >= n) return;
    int head = l >> 3;
    float4 at  = *reinterpret_cast<const float4*>(attn + head * 32 + (l & 7) * 4);
    float4 fdv = *reinterpret_cast<const float4*>(base + (size_t)v * 1024 + 512 + l * 4);
    float4 acc = make_float4(0.f, 0.f, 0.f, 0.f);
    float dn = 0.f;
    int s0 = rowstart[v], s1 = rowstart[v + 1];
    int u = (s0 < s1) ? csrc[s0] : 0;
    float4 sv = (s0 < s1) ? *reinterpret_cast<const float4*>(base + (size_t)u * 1024 + l * 4)
                          : make_float4(0.f, 0.f, 0.f, 0.f);
    for (int i = s0; i < s1; ++i) {
        int un = (i + 1 < s1) ? csrc[i + 1] : 0;
        float4 svn = (i + 1 < s1) ? *reinterpret_cast<const float4*>(base + (size_t)un * 1024 + l * 4)
                                  : make_float4(0.f, 0.f, 0.f, 0.f);
        float ex_, ey, ez, ew;
        ex_ = sv.x + fdv.x; ex_ = (ex_ > 0.f) ? ex_ : 0.2f * ex_;
        ey  = sv.y + fdv.y; ey  = (ey  > 0.f) ? ey  : 0.2f * ey;
        ez  = sv.z + fdv.z; ez  = (ez  > 0.f) ? ez  : 0.2f * ez;
        ew  = sv.w + fdv.w; ew  = (ew  > 0.f) ? ew  : 0.2f * ew;
        float p = ex_ * at.x + ey * at.y + ez * at.z + ew * at.w;
        p += __shfl_xor(p, 1, 8);
        p += __shfl_xor(p, 2, 8);
        p += __shfl_xor(p, 4, 8);
        float ex = __expf(p);
        acc.x += ex * sv.x; acc.y += ex * sv.y; acc.z += ex * sv.z; acc.w += ex * sv.w;
        dn += ex;
        sv = svn; u = un;
    }
    *reinterpret_cast<float4*>(num + (size_t)v * 512 + l * 4) = acc;
    if ((l & 7) == 0) den[(size_t)v * 16 + head] = dn;
}

__global__ void gat_fin4(const float* __restrict__ den, const float* __restrict__ res,
                         float* __restrict__ num, int n)
{
    int gid = blockIdx.x * blockDim.x + threadIdx.x;
    if (gid >= n * 128) return;
    int v = gid >> 7, l = gid & 127, head = l >> 3;
    float d = den[(size_t)v * 16 + head];
    float inv = (d > 0.f) ? __fdividef(1.f, d) : 0.f;
    float4 o = reinterpret_cast<float4*>(num)[gid];
    float4 r = reinterpret_cast<const float4*>(res)[gid];
    o.x = fmaxf(o.x * inv + r.x, 0.f);
    o.y = fmaxf(o.y * inv + r.y, 0.f);
    o.z = fmaxf(o.z * inv + r.z, 0.f);
    o.w = fmaxf(o.w * inv + r.w, 0.f);
    reinterpret_cast<float4*>(num)[gid] = o;
}

// ---------------- final classifier
__global__ void final_lin(const float* __restrict__ h1, const float* __restrict__ newF,
                          const float* __restrict__ h3, const float* __restrict__ W,
                          const float* __restrict__ bias, float* __restrict__ out, int n)
{
    int gid = blockIdx.x * blockDim.x + threadIdx.x;
    if (gid >= n * 6) return;
    int v = gid / 6, o = gid - v * 6;
    float s = bias[o];
    const float* a = h1 + (size_t)v * 64;
#pragma unroll 8
    for (int r = 0; r < 64; ++r) s += a[r] * W[r * 6 + o];
    const float* b = newF + (size_t)v * 8;
#pragma unroll
    for (int r = 0; r < 8; ++r) s += b[r] * W[(64 + r) * 6 + o];
    const float* c = h3 + (size_t)v * 64;
#pragma unroll 8
    for (int r = 0; r < 64; ++r) s += c[r] * W[(72 + r) * 6 + o];
    out[gid] = s;
}

// ----------------------------------------------------------------------------
extern "C" void kernel_launch(void* const* d_in, const int* in_sizes, int n_in,
                              void* d_out, int out_size, void* d_ws, size_t ws_size,
                              hipStream_t stream)
{
    const float* text   = (const float*)d_in[0];
    const float* audio  = (const float*)d_in[1];
    const float* vision = (const float*)d_in[2];
    const int*   esrc   = (const int*)d_in[3];
    const int*   edst   = (const int*)d_in[4];
    const float* W_audio = (const float*)d_in[5];  const float* b_audio = (const float*)d_in[6];
    const float* W_vision= (const float*)d_in[7];  const float* b_vision= (const float*)d_in[8];
    const float* W_text  = (const float*)d_in[9];  const float* b_text  = (const float*)d_in[10];
    const float* Wih_f = (const float*)d_in[11]; const float* Whh_f = (const float*)d_in[12];
    const float* bih_f = (const float*)d_in[13]; const float* bhh_f = (const float*)d_in[14];
    const float* Wih_b = (const float*)d_in[15]; const float* Whh_b = (const float*)d_in[16];
    const float* bih_b = (const float*)d_in[17]; const float* bhh_b = (const float*)d_in[18];
    const float* W_gc  = (const float*)d_in[19]; const float* b_gc  = (const float*)d_in[20];
    const float* Wsrc2 = (const float*)d_in[21]; const float* bsrc2 = (const float*)d_in[22];
    const float* Wdst2 = (const float*)d_in[23]; const float* bdst2 = (const float*)d_in[24];
    const float* attn2 = (const float*)d_in[25]; const float* Wres2 = (const float*)d_in[26];
    const float* Wsrc0 = (const float*)d_in[27]; const float* bsrc0 = (const float*)d_in[28];
    const float* Wdst0 = (const float*)d_in[29]; const float* bdst0 = (const float*)d_in[30];
    const float* attn0 = (const float*)d_in[31]; const float* Wres0 = (const float*)d_in[32];
    const float* Wsrc1 = (const float*)d_in[33]; const float* bsrc1 = (const float*)d_in[34];
    const float* Wdst1 = (const float*)d_in[35]; const float* bdst1 = (const float*)d_in[36];
    const float* attn1 = (const float*)d_in[37]; const float* Wres1 = (const float*)d_in[38];
    const float* W_lin = (const float*)d_in[39]; const float* b_lin = (const float*)d_in[40];
    float* out = (float*)d_out;

    const int n = in_sizes[0] / 1024;   // 12000
    const int E = in_sizes[3];          // 192000
    const int B = n / 120;              // 100

    // ---- workspace carve (256B aligned) — ~102 MB total, unchanged
    char* p = (char*)d_ws;
    auto alloc_f = [&](size_t cnt) { float* r = (float*)p; p += ((cnt * 4 + 255) / 256) * 256; return r; };
    auto alloc_i = [&](size_t cnt) { int* r = (int*)p; p += ((cnt * 4 + 255) / 256) * 256; return r; };
    float* stackFT = alloc_f((size_t)n * 192);
    float* hbuf    = alloc_f((size_t)n * 192);
    float* xWf     = alloc_f((size_t)n * 16);
    float* xWb     = alloc_f((size_t)n * 16);
    float* newF    = alloc_f((size_t)n * 8);
    float* big0    = alloc_f((size_t)n * 512);   // big0..big2 contiguous
    float* big1    = alloc_f((size_t)n * 512);
    float* big2    = alloc_f((size_t)n * 512);
    float* den     = alloc_f((size_t)n * 16);
    float* h3      = alloc_f((size_t)n * 64);
    float* h1s     = alloc_f((size_t)n * 64);    // doubles as packed-weight scratch until gat1 edge
    float* rs_out  = alloc_f(n);
    float* rs_in   = alloc_f(n);
    int* zero_base = alloc_i((size_t)3 * n);
    int* degout = zero_base;
    int* degin  = zero_base + n;
    int* cursor = zero_base + 2 * n;
    int* rowstart = alloc_i((size_t)n + 1);
    int* perm     = alloc_i((size_t)E);
    if ((size_t)(p - (char*)d_ws) > ws_size) return;
    (void)big1;

    float* pw = h1s;
    float* pb = h1s + 200704;

    // ---- graph preprocessing
    hipMemsetAsync(zero_base, 0, (size_t)3 * n * 4, stream);
    deg_kernel<<<(E + 255) / 256, 256, 0, stream>>>(esrc, edst, degout, degin, E);
    scan_kernel<<<1, 1024, 0, stream>>>(degin, rowstart, n);
    perm_kernel<<<(E + 255) / 256, 256, 0, stream>>>(edst, rowstart, cursor, perm, E);
    gather_src_kernel<<<(E + 255) / 256, 256, 0, stream>>>(esrc, perm, E);
    rs_kernel<<<(n + 255) / 256, 256, 0, stream>>>(degout, degin, rs_out, rs_in, n);
    const int* csrc = perm;

    auto mgemm = [&](const float* A, const float* Bm, const float* bias, const float* rsc,
                     float* Cp, int M, int Nb, int K, int ldc) {
        dim3 grid((M + 127) / 128, Nb / 64);
        mfma_gemm<<<grid, 256, 0, stream>>>(A, Bm, bias, rsc, Cp, M, Nb, K, ldc, 0);
    };

    // ---- modality encoders -> stackFT [n,192] (f32, memory-bound)
    {
        dim3 grid((n + 63) / 64, 1, 3);
        enc3_kernel<<<grid, 256, 0, stream>>>(text, audio, vision, W_text, W_audio, W_vision,
                                              b_text, b_audio, b_vision, stackFT, n);
    }

    // ---- BiLSTM
    lstm_pre<<<(n * 32 + 255) / 256, 256, 0, stream>>>(stackFT, Wih_f, Wih_b,
                                                       bih_f, bhh_f, bih_b, bhh_b, xWf, xWb, n);
    lstm_seq2<<<(2 * B + 3) / 4, 64, 0, stream>>>(xWf, xWb, Whh_f, Whh_b, newF, B);

    // ---- GraphConv imputation + L1 norm -> hbuf
    mgemm(stackFT, W_gc, nullptr, rs_out, big0, n, 192, 192, 192);
    gc_combine2<<<(n + 3) / 4, 256, 0, stream>>>(stackFT, big0, rowstart, csrc, rs_in, b_gc, hbuf, n);

    // ---- gat2: packed src|dst|res GEMM -> stackFT [n,192], fused edge -> h3
    pack3_kernel<<<(192 * 192 + 255) / 256, 256, 0, stream>>>(Wsrc2, Wdst2, Wres2, bsrc2, bdst2, pw, pb, 192, 64);
    mgemm(hbuf, pw, pb, nullptr, stackFT, n, 192, 192, 192);
    gat_edge4<<<(n + 15) / 16, 256, 0, stream>>>(stackFT, 192, attn2, rowstart, csrc, h3, n);

    // ---- gat0: packed src|dst GEMM -> big0 [n,1024]; edge -> big2; res GEMM -> big0; fin
    pack2_kernel<<<(192 * 1024 + 255) / 256, 256, 0, stream>>>(Wsrc0, Wdst0, bsrc0, bdst0, pw, pb, 192, 512);
    mgemm(hbuf, pw, pb, nullptr, big0, n, 1024, 192, 1024);
    gat_edge32<<<(n + 1) / 2, 256, 0, stream>>>(big0, attn0, rowstart, csrc, big2, den, n);
    mgemm(hbuf, Wres0, nullptr, nullptr, big0, n, 512, 192, 512);
    gat_fin4<<<(n * 128 + 255) / 256, 256, 0, stream>>>(den, big0, big2, n);

    // ---- gat1: packed src|dst|res GEMM -> big0 [n,192], fused edge -> h1s
    pack3_kernel<<<(512 * 192 + 255) / 256, 256, 0, stream>>>(Wsrc1, Wdst1, Wres1, bsrc1, bdst1, pw, pb, 512, 64);
    mgemm(big2, pw, pb, nullptr, big0, n, 192, 512, 192);
    gat_edge4<<<(n + 15) / 16, 256, 0, stream>>>(big0, 192, attn1, rowstart, csrc, h1s, n);

    // ---- final classifier
    final_lin<<<(n * 6 + 255) / 256, 256, 0, stream>>>(h1s, newF, h3, W_lin, b_lin, out, n);
}

// Round 4
// 490.374 us; speedup vs baseline: 2.4497x; 1.0504x over previous
//
#include <hip/hip_runtime.h>

typedef __attribute__((ext_vector_type(8))) short short8;
typedef __attribute__((ext_vector_type(4))) float f32x4;

__device__ __forceinline__ unsigned short f2bf(float f) {
    unsigned u = __float_as_uint(f);
    u += 0x7FFFu + ((u >> 16) & 1u);
    return (unsigned short)(u >> 16);
}
__device__ __forceinline__ float bf2f(unsigned short h) {
    return __uint_as_float((unsigned)h << 16);
}

// ---------------- bf16 MFMA GEMM: C[M,Nb] = A[M,K]@B[K,Nb] (+bias)(*rowscale), f32 in
// BM=128, BN=64, BK=32; 256 thr = 4 waves; OBF16 selects f32 or bf16 output
template<bool OBF16>
__global__ __launch_bounds__(256)
void mfma_gemm(const float* __restrict__ A, const float* __restrict__ B,
               const float* __restrict__ bias, const float* __restrict__ rowscale,
               void* __restrict__ Cv, int M, int Nb, int K, int ldc, int ccol)
{
    __shared__ alignas(16) unsigned short Al[4][128][8];  // [kgrp][m][e]
    __shared__ alignas(16) unsigned short Bl[4][64][8];   // [kgrp][c][e]
    const int t = threadIdx.x;
    const int w = t >> 6, l = t & 63;
    const int row0 = blockIdx.x * 128;
    const int col0 = blockIdx.y * 64;
    f32x4 acc[2][4] = {};
    for (int k0 = 0; k0 < K; k0 += 32) {
#pragma unroll
        for (int s = 0; s < 4; ++s) {
            int idx = s * 256 + t;
            int m = idx >> 3, kq = idx & 7;
            int gm = row0 + m;
            float4 av = make_float4(0.f, 0.f, 0.f, 0.f);
            if (gm < M) av = *reinterpret_cast<const float4*>(A + (size_t)gm * K + k0 + kq * 4);
            ushort4 pk = make_ushort4(f2bf(av.x), f2bf(av.y), f2bf(av.z), f2bf(av.w));
            *reinterpret_cast<ushort4*>(&Al[kq >> 1][m][(kq & 1) * 4]) = pk;
        }
        if (t < 128) {
            int kb = (t >> 4) * 4;
            int cb = (t & 15) * 4;
            const float* bp = B + (size_t)(k0 + kb) * Nb + col0 + cb;
            float4 r0 = *reinterpret_cast<const float4*>(bp);
            float4 r1 = *reinterpret_cast<const float4*>(bp + Nb);
            float4 r2 = *reinterpret_cast<const float4*>(bp + 2 * (size_t)Nb);
            float4 r3 = *reinterpret_cast<const float4*>(bp + 3 * (size_t)Nb);
            int g = kb >> 3, hh = (kb >> 2) & 1;
            *reinterpret_cast<ushort4*>(&Bl[g][cb + 0][hh * 4]) = make_ushort4(f2bf(r0.x), f2bf(r1.x), f2bf(r2.x), f2bf(r3.x));
            *reinterpret_cast<ushort4*>(&Bl[g][cb + 1][hh * 4]) = make_ushort4(f2bf(r0.y), f2bf(r1.y), f2bf(r2.y), f2bf(r3.y));
            *reinterpret_cast<ushort4*>(&Bl[g][cb + 2][hh * 4]) = make_ushort4(f2bf(r0.z), f2bf(r1.z), f2bf(r2.z), f2bf(r3.z));
            *reinterpret_cast<ushort4*>(&Bl[g][cb + 3][hh * 4]) = make_ushort4(f2bf(r0.w), f2bf(r1.w), f2bf(r2.w), f2bf(r3.w));
        }
        __syncthreads();
        int kg = l >> 4, r16 = l & 15;
        short8 a0 = *reinterpret_cast<const short8*>(&Al[kg][w * 32 + r16][0]);
        short8 a1 = *reinterpret_cast<const short8*>(&Al[kg][w * 32 + 16 + r16][0]);
        short8 b0 = *reinterpret_cast<const short8*>(&Bl[kg][r16][0]);
        short8 b1 = *reinterpret_cast<const short8*>(&Bl[kg][16 + r16][0]);
        short8 b2 = *reinterpret_cast<const short8*>(&Bl[kg][32 + r16][0]);
        short8 b3 = *reinterpret_cast<const short8*>(&Bl[kg][48 + r16][0]);
        acc[0][0] = __builtin_amdgcn_mfma_f32_16x16x32_bf16(a0, b0, acc[0][0], 0, 0, 0);
        acc[0][1] = __builtin_amdgcn_mfma_f32_16x16x32_bf16(a0, b1, acc[0][1], 0, 0, 0);
        acc[0][2] = __builtin_amdgcn_mfma_f32_16x16x32_bf16(a0, b2, acc[0][2], 0, 0, 0);
        acc[0][3] = __builtin_amdgcn_mfma_f32_16x16x32_bf16(a0, b3, acc[0][3], 0, 0, 0);
        acc[1][0] = __builtin_amdgcn_mfma_f32_16x16x32_bf16(a1, b0, acc[1][0], 0, 0, 0);
        acc[1][1] = __builtin_amdgcn_mfma_f32_16x16x32_bf16(a1, b1, acc[1][1], 0, 0, 0);
        acc[1][2] = __builtin_amdgcn_mfma_f32_16x16x32_bf16(a1, b2, acc[1][2], 0, 0, 0);
        acc[1][3] = __builtin_amdgcn_mfma_f32_16x16x32_bf16(a1, b3, acc[1][3], 0, 0, 0);
        __syncthreads();
    }
#pragma unroll
    for (int mi = 0; mi < 2; ++mi)
#pragma unroll
        for (int ni = 0; ni < 4; ++ni) {
            int col = col0 + ni * 16 + (l & 15);
            float bv = bias ? bias[col] : 0.f;
#pragma unroll
            for (int r = 0; r < 4; ++r) {
                int gm = row0 + w * 32 + mi * 16 + (l >> 4) * 4 + r;
                if (gm < M) {
                    float rs = rowscale ? rowscale[gm] : 1.f;
                    float val = (acc[mi][ni][r] + bv) * rs;
                    if (OBF16) ((unsigned short*)Cv)[(size_t)gm * ldc + ccol + col] = f2bf(val);
                    else       ((float*)Cv)[(size_t)gm * ldc + ccol + col] = val;
                }
            }
        }
}

// ---------------- encoder: split-precision bf16x3 MFMA, BM=64, z = modality
__global__ __launch_bounds__(256)
void enc_mfma(const float* __restrict__ text, const float* __restrict__ audio, const float* __restrict__ vision,
              const float* __restrict__ Wt, const float* __restrict__ Wa, const float* __restrict__ Wv,
              const float* __restrict__ bt, const float* __restrict__ ba, const float* __restrict__ bv,
              float* __restrict__ C, int M)
{
    int z = blockIdx.z;
    const float* A  = (z == 0) ? text : (z == 1) ? audio : vision;
    const float* W  = (z == 0) ? Wt   : (z == 1) ? Wa    : Wv;
    const float* bb = (z == 0) ? bt   : (z == 1) ? ba    : bv;
    const int K = (z == 1) ? 512 : 1024;

    __shared__ alignas(16) unsigned short Ah[4][64][8], Ao[4][64][8];
    __shared__ alignas(16) unsigned short Bh[4][64][8], Bo[4][64][8];
    const int t = threadIdx.x;
    const int w = t >> 6, l = t & 63;
    const int row0 = blockIdx.x * 64;
    f32x4 acc[4] = {};
    for (int k0 = 0; k0 < K; k0 += 32) {
        // A: 64 rows x 32 k = 512 float4, 2 per thread; split hi/lo
#pragma unroll
        for (int s = 0; s < 2; ++s) {
            int idx = s * 256 + t;
            int m = idx >> 3, kq = idx & 7;
            int gm = row0 + m;
            float4 av = make_float4(0.f, 0.f, 0.f, 0.f);
            if (gm < M) av = *reinterpret_cast<const float4*>(A + (size_t)gm * K + k0 + kq * 4);
            ushort4 hi = make_ushort4(f2bf(av.x), f2bf(av.y), f2bf(av.z), f2bf(av.w));
            ushort4 lo = make_ushort4(f2bf(av.x - bf2f(hi.x)), f2bf(av.y - bf2f(hi.y)),
                                      f2bf(av.z - bf2f(hi.z)), f2bf(av.w - bf2f(hi.w)));
            *reinterpret_cast<ushort4*>(&Ah[kq >> 1][m][(kq & 1) * 4]) = hi;
            *reinterpret_cast<ushort4*>(&Ao[kq >> 1][m][(kq & 1) * 4]) = lo;
        }
        // B (W[K][64]): threads 0..127 transpose 4k x 4c, split hi/lo
        if (t < 128) {
            int kb = (t >> 4) * 4;
            int cb = (t & 15) * 4;
            const float* bp = W + (size_t)(k0 + kb) * 64 + cb;
            float4 r0 = *reinterpret_cast<const float4*>(bp);
            float4 r1 = *reinterpret_cast<const float4*>(bp + 64);
            float4 r2 = *reinterpret_cast<const float4*>(bp + 128);
            float4 r3 = *reinterpret_cast<const float4*>(bp + 192);
            int g = kb >> 3, hh = (kb >> 2) & 1;
            float cc[4][4] = {{r0.x, r1.x, r2.x, r3.x}, {r0.y, r1.y, r2.y, r3.y},
                              {r0.z, r1.z, r2.z, r3.z}, {r0.w, r1.w, r2.w, r3.w}};
#pragma unroll
            for (int j = 0; j < 4; ++j) {
                ushort4 hi = make_ushort4(f2bf(cc[j][0]), f2bf(cc[j][1]), f2bf(cc[j][2]), f2bf(cc[j][3]));
                ushort4 lo = make_ushort4(f2bf(cc[j][0] - bf2f(hi.x)), f2bf(cc[j][1] - bf2f(hi.y)),
                                          f2bf(cc[j][2] - bf2f(hi.z)), f2bf(cc[j][3] - bf2f(hi.w)));
                *reinterpret_cast<ushort4*>(&Bh[g][cb + j][hh * 4]) = hi;
                *reinterpret_cast<ushort4*>(&Bo[g][cb + j][hh * 4]) = lo;
            }
        }
        __syncthreads();
        int kg = l >> 4, r16 = l & 15;
        short8 ah = *reinterpret_cast<const short8*>(&Ah[kg][w * 16 + r16][0]);
        short8 ao = *reinterpret_cast<const short8*>(&Ao[kg][w * 16 + r16][0]);
#pragma unroll
        for (int ni = 0; ni < 4; ++ni) {
            short8 bh = *reinterpret_cast<const short8*>(&Bh[kg][ni * 16 + r16][0]);
            short8 bo = *reinterpret_cast<const short8*>(&Bo[kg][ni * 16 + r16][0]);
            acc[ni] = __builtin_amdgcn_mfma_f32_16x16x32_bf16(ah, bh, acc[ni], 0, 0, 0);
            acc[ni] = __builtin_amdgcn_mfma_f32_16x16x32_bf16(ah, bo, acc[ni], 0, 0, 0);
            acc[ni] = __builtin_amdgcn_mfma_f32_16x16x32_bf16(ao, bh, acc[ni], 0, 0, 0);
        }
        __syncthreads();
    }
#pragma unroll
    for (int ni = 0; ni < 4; ++ni) {
        int col = ni * 16 + (l & 15);
        float bvv = bb[col];
#pragma unroll
        for (int r = 0; r < 4; ++r) {
            int gm = row0 + w * 16 + (l >> 4) * 4 + r;
            if (gm < M) C[(size_t)gm * 192 + z * 64 + col] = acc[ni][r] + bvv;
        }
    }
}

// ---------------- weight packing
__global__ void pack3_kernel(const float* __restrict__ W0, const float* __restrict__ W1, const float* __restrict__ W2,
                             const float* __restrict__ b0, const float* __restrict__ b1,
                             float* __restrict__ Wp, float* __restrict__ bp, int K, int O)
{
    int gid = blockIdx.x * blockDim.x + threadIdx.x;
    int O3 = 3 * O;
    if (gid < O3) bp[gid] = (gid < O) ? b0[gid] : (gid < 2 * O) ? b1[gid - O] : 0.f;
    if (gid >= K * O3) return;
    int k = gid / O3, c = gid - k * O3;
    float v = (c < O) ? W0[k * O + c] : (c < 2 * O) ? W1[k * O + c - O] : W2[k * O + c - 2 * O];
    Wp[gid] = v;
}

__global__ void pack2_kernel(const float* __restrict__ W0, const float* __restrict__ W1,
                             const float* __restrict__ b0, const float* __restrict__ b1,
                             float* __restrict__ Wp, float* __restrict__ bp, int K, int O)
{
    int gid = blockIdx.x * blockDim.x + threadIdx.x;
    int O2 = 2 * O;
    if (gid < O2) bp[gid] = (gid < O) ? b0[gid] : b1[gid - O];
    if (gid >= K * O2) return;
    int k = gid / O2, c = gid - k * O2;
    Wp[gid] = (c < O) ? W0[k * O + c] : W1[k * O + c - O];
}

// ---------------- graph preprocessing
__global__ void deg_kernel(const int* __restrict__ src, const int* __restrict__ dst,
                           int* degout, int* degin, int E)
{
    int e = blockIdx.x * blockDim.x + threadIdx.x;
    if (e < E) {
        atomicAdd(&degout[src[e]], 1);
        atomicAdd(&degin[dst[e]], 1);
    }
}

__global__ __launch_bounds__(1024)
void scan_kernel(const int* __restrict__ degin, int* __restrict__ rowstart, int n)
{
    __shared__ int part[1024];
    int t = threadIdx.x;
    int chunk = (n + 1023) / 1024;
    int s = 0;
    for (int i = 0; i < chunk; ++i) {
        int idx = t * chunk + i;
        if (idx < n) s += degin[idx];
    }
    part[t] = s;
    __syncthreads();
    for (int o = 1; o < 1024; o <<= 1) {
        int v = (t >= o) ? part[t - o] : 0;
        __syncthreads();
        part[t] += v;
        __syncthreads();
    }
    int run = (t > 0) ? part[t - 1] : 0;
    for (int i = 0; i < chunk; ++i) {
        int idx = t * chunk + i;
        if (idx < n) { rowstart[idx] = run; run += degin[idx]; }
    }
    if (t == 1023) rowstart[n] = part[1023];
}

__global__ void perm_kernel(const int* __restrict__ dst, const int* __restrict__ rowstart,
                            int* cursor, int* __restrict__ perm, int E)
{
    int e = blockIdx.x * blockDim.x + threadIdx.x;
    if (e < E) {
        int v = dst[e];
        int p = atomicAdd(&cursor[v], 1);
        perm[rowstart[v] + p] = e;
    }
}

__global__ void gather_src_kernel(const int* __restrict__ esrc, int* perm, int E)
{
    int i = blockIdx.x * blockDim.x + threadIdx.x;
    if (i < E) perm[i] = esrc[perm[i]];
}

__global__ void rs_kernel(const int* degout, const int* degin, float* rso, float* rsi, int n)
{
    int i = blockIdx.x * blockDim.x + threadIdx.x;
    if (i < n) {
        rso[i] = rsqrtf((float)max(degout[i], 1));
        rsi[i] = rsqrtf((float)max(degin[i], 1));
    }
}

// ---------------- LSTM
__global__ void lstm_pre(const float* __restrict__ x, const float* __restrict__ Wf,
                         const float* __restrict__ Wb,
                         const float* bf1, const float* bf2, const float* bb1, const float* bb2,
                         float* __restrict__ xWf, float* __restrict__ xWb, int n)
{
    int gid = blockIdx.x * blockDim.x + threadIdx.x;
    if (gid >= n * 32) return;
    int nn = gid >> 5, r = gid & 31, d = r >> 4, j = r & 15;
    const float* W = (d ? Wb : Wf) + j * 192;
    const float* xr = x + (size_t)nn * 192;
    float s = 0.f;
#pragma unroll 4
    for (int k = 0; k < 192; k += 4) {
        float4 xv = *reinterpret_cast<const float4*>(xr + k);
        float4 wv = *reinterpret_cast<const float4*>(W + k);
        s += xv.x * wv.x + xv.y * wv.y + xv.z * wv.z + xv.w * wv.w;
    }
    s += d ? (bb1[j] + bb2[j]) : (bf1[j] + bf2[j]);
    int b = nn / 120, tt = nn - b * 120;
    (d ? xWb : xWf)[((size_t)b * 16 + j) * 120 + tt] = s;
}

__device__ __forceinline__ float fsigm(float x) { return __fdividef(1.f, 1.f + __expf(-x)); }
__device__ __forceinline__ float ftanh(float x) { return 1.f - __fdividef(2.f, __expf(2.f * x) + 1.f); }

template<int DIR>
__device__ void lstm_chain(const float* __restrict__ xw, const float* __restrict__ whh,
                           float* __restrict__ newF, int b)
{
    int j = threadIdx.x & 15;
    int k = j & 3;
    float4 w = *reinterpret_cast<const float4*>(whh + j * 4);
    const float* xp = xw + ((size_t)b * 16 + j) * 120;
    float h0 = 0.f, h1 = 0.f, h2 = 0.f, h3 = 0.f, cst = 0.f;
    int tb0 = DIR ? 108 : 0;
    float4 a0 = *reinterpret_cast<const float4*>(xp + tb0);
    float4 a1 = *reinterpret_cast<const float4*>(xp + tb0 + 4);
    float4 a2 = *reinterpret_cast<const float4*>(xp + tb0 + 8);
    for (int ch = 0; ch < 10; ++ch) {
        float4 b0 = a0, b1 = a1, b2 = a2;
        if (ch < 9) {
            int nt = DIR ? (96 - ch * 12) : (12 + ch * 12);
            b0 = *reinterpret_cast<const float4*>(xp + nt);
            b1 = *reinterpret_cast<const float4*>(xp + nt + 4);
            b2 = *reinterpret_cast<const float4*>(xp + nt + 8);
        }
        float zz[12] = {a0.x, a0.y, a0.z, a0.w, a1.x, a1.y, a1.z, a1.w, a2.x, a2.y, a2.z, a2.w};
        int tbase = DIR ? (108 - ch * 12) : (ch * 12);
#pragma unroll
        for (int ii = 0; ii < 12; ++ii) {
            int idx = DIR ? (11 - ii) : ii;
            float z = zz[idx] + ((w.x * h0 + w.y * h1) + (w.z * h2 + w.w * h3));
            float zi = __shfl(z, k, 16);
            float zf = __shfl(z, k + 4, 16);
            float zg = __shfl(z, k + 8, 16);
            float zo = __shfl(z, k + 12, 16);
            float ig = fsigm(zi), fg = fsigm(zf), gg = ftanh(zg), og = fsigm(zo);
            cst = fg * cst + ig * gg;
            float hn = og * ftanh(cst);
            h0 = __shfl(hn, 0, 16); h1 = __shfl(hn, 1, 16);
            h2 = __shfl(hn, 2, 16); h3 = __shfl(hn, 3, 16);
            if (j < 4) newF[((size_t)b * 120 + tbase + idx) * 8 + DIR * 4 + j] = hn;
        }
        a0 = b0; a1 = b1; a2 = b2;
    }
}

__global__ __launch_bounds__(64)
void lstm_seq2(const float* __restrict__ xWf, const float* __restrict__ xWb,
               const float* __restrict__ Whhf, const float* __restrict__ Whhb,
               float* __restrict__ newF, int B)
{
    int sub = threadIdx.x >> 4;
    int chain = blockIdx.x * 4 + sub;
    if (chain >= 2 * B) return;
    int d = chain / B;
    int b = chain - d * B;
    if (d == 0) lstm_chain<0>(xWf, Whhf, newF, b);
    else        lstm_chain<1>(xWb, Whhb, newF, b);
}

// ---------------- GraphConv combine + L1 norm: one wave per node, 3 feats/lane
__global__ __launch_bounds__(256)
void gc_combine2(const float* __restrict__ stackFT, const float* __restrict__ hw,
                 const int* __restrict__ rowstart, const int* __restrict__ csrc,
                 const float* __restrict__ rs_in,
                 const float* __restrict__ b_gc, float* __restrict__ h, int n)
{
    int v = blockIdx.x * 4 + (threadIdx.x >> 6);
    int l = threadIdx.x & 63;
    if (v >= n) return;
    int s0 = rowstart[v], s1 = rowstart[v + 1];
    float sum0 = 0.f, sum1 = 0.f, sum2 = 0.f;
    int u = (s0 < s1) ? csrc[s0] : 0;
    for (int i = s0; i < s1; ++i) {
        int un = (i + 1 < s1) ? csrc[i + 1] : 0;
        const float* hr = hw + (size_t)u * 192 + l;
        float p0 = hr[0], p1 = hr[64], p2 = hr[128];
        sum0 += p0; sum1 += p1; sum2 += p2;
        u = un;
    }
    float ri = rs_in[v];
    const float* sf = stackFT + (size_t)v * 192 + l;
    float v0 = 0.5f * (sf[0]   + sum0 * ri + b_gc[l]);
    float v1 = 0.5f * (sf[64]  + sum1 * ri + b_gc[l + 64]);
    float v2 = 0.5f * (sf[128] + sum2 * ri + b_gc[l + 128]);
    float r = fabsf(v0) + fabsf(v1) + fabsf(v2);
#pragma unroll
    for (int o = 32; o; o >>= 1) r += __shfl_xor(r, o);
    float inv = __fdividef(1.f, fmaxf(r, 1e-12f));
    float* hp = h + (size_t)v * 192 + l;
    hp[0] = v0 * inv; hp[64] = v1 * inv; hp[128] = v2 * inv;
}

// ---------------- GATv2 F=4 (HF=64): 16 lanes/node, one head per lane, fused epilogue
__global__ __launch_bounds__(256)
void gat_edge4(const float* __restrict__ base, int ld,   // fs|fd|res packed, f32
               const float* __restrict__ attn,
               const int* __restrict__ rowstart, const int* __restrict__ csrc,
               float* __restrict__ outp, int n)
{
    int v = blockIdx.x * 16 + (threadIdx.x >> 4);
    int l = threadIdx.x & 15;
    if (v >= n) return;
    float4 at  = *reinterpret_cast<const float4*>(attn + l * 4);
    float4 fdv = *reinterpret_cast<const float4*>(base + (size_t)v * ld + 64 + l * 4);
    float4 acc = make_float4(0.f, 0.f, 0.f, 0.f);
    float dn = 0.f;
    int s0 = rowstart[v], s1 = rowstart[v + 1];
    int u = (s0 < s1) ? csrc[s0] : 0;
    float4 sv = (s0 < s1) ? *reinterpret_cast<const float4*>(base + (size_t)u * ld + l * 4)
                          : make_float4(0.f, 0.f, 0.f, 0.f);
    for (int i = s0; i < s1; ++i) {
        int un = (i + 1 < s1) ? csrc[i + 1] : 0;
        float4 svn = (i + 1 < s1) ? *reinterpret_cast<const float4*>(base + (size_t)un * ld + l * 4)
                                  : make_float4(0.f, 0.f, 0.f, 0.f);
        float ex_, ey, ez, ew;
        ex_ = sv.x + fdv.x; ex_ = (ex_ > 0.f) ? ex_ : 0.2f * ex_;
        ey  = sv.y + fdv.y; ey  = (ey  > 0.f) ? ey  : 0.2f * ey;
        ez  = sv.z + fdv.z; ez  = (ez  > 0.f) ? ez  : 0.2f * ez;
        ew  = sv.w + fdv.w; ew  = (ew  > 0.f) ? ew  : 0.2f * ew;
        float p = ex_ * at.x + ey * at.y + ez * at.z + ew * at.w;
        float ex = __expf(p);
        acc.x += ex * sv.x; acc.y += ex * sv.y; acc.z += ex * sv.z; acc.w += ex * sv.w;
        dn += ex;
        sv = svn; u = un;
    }
    float4 r = *reinterpret_cast<const float4*>(base + (size_t)v * ld + 128 + l * 4);
    float inv = (dn > 0.f) ? __fdividef(1.f, dn) : 0.f;
    float4 o;
    o.x = fmaxf(acc.x * inv + r.x, 0.f);
    o.y = fmaxf(acc.y * inv + r.y, 0.f);
    o.z = fmaxf(acc.z * inv + r.z, 0.f);
    o.w = fmaxf(acc.w * inv + r.w, 0.f);
    *reinterpret_cast<float4*>(outp + (size_t)v * 64 + l * 4) = o;
}

// ---------------- GATv2 F=32 (HF=512): bf16 fs|fd, 128 lanes/node, 8-lane head reduce
__global__ __launch_bounds__(256)
void gat_edge32(const unsigned short* __restrict__ base,   // [n,1024] bf16 fs|fd
                const float* __restrict__ attn,
                const int* __restrict__ rowstart, const int* __restrict__ csrc,
                float* __restrict__ num, float* __restrict__ den, int n)
{
    int v = blockIdx.x * 2 + (threadIdx.x >> 7);
    int l = threadIdx.x & 127;
    if (v >= n) return;
    int head = l >> 3;
    float4 at = *reinterpret_cast<const float4*>(attn + head * 32 + (l & 7) * 4);
    ushort4 fdu = *reinterpret_cast<const ushort4*>(base + (size_t)v * 1024 + 512 + l * 4);
    float4 fdv = make_float4(bf2f(fdu.x), bf2f(fdu.y), bf2f(fdu.z), bf2f(fdu.w));
    float4 acc = make_float4(0.f, 0.f, 0.f, 0.f);
    float dn = 0.f;
    int s0 = rowstart[v], s1 = rowstart[v + 1];
    int u = (s0 < s1) ? csrc[s0] : 0;
    ushort4 su = (s0 < s1) ? *reinterpret_cast<const ushort4*>(base + (size_t)u * 1024 + l * 4)
                           : make_ushort4(0, 0, 0, 0);
    for (int i = s0; i < s1; ++i) {
        int un = (i + 1 < s1) ? csrc[i + 1] : 0;
        ushort4 sun = (i + 1 < s1) ? *reinterpret_cast<const ushort4*>(base + (size_t)un * 1024 + l * 4)
                                   : make_ushort4(0, 0, 0, 0);
        float4 sv = make_float4(bf2f(su.x), bf2f(su.y), bf2f(su.z), bf2f(su.w));
        float ex_, ey, ez, ew;
        ex_ = sv.x + fdv.x; ex_ = (ex_ > 0.f) ? ex_ : 0.2f * ex_;
        ey  = sv.y + fdv.y; ey  = (ey  > 0.f) ? ey  : 0.2f * ey;
        ez  = sv.z + fdv.z; ez  = (ez  > 0.f) ? ez  : 0.2f * ez;
        ew  = sv.w + fdv.w; ew  = (ew  > 0.f) ? ew  : 0.2f * ew;
        float p = ex_ * at.x + ey * at.y + ez * at.z + ew * at.w;
        p += __shfl_xor(p, 1, 8);
        p += __shfl_xor(p, 2, 8);
        p += __shfl_xor(p, 4, 8);
        float ex = __expf(p);
        acc.x += ex * sv.x; acc.y += ex * sv.y; acc.z += ex * sv.z; acc.w += ex * sv.w;
        dn += ex;
        su = sun; u = un;
    }
    *reinterpret_cast<float4*>(num + (size_t)v * 512 + l * 4) = acc;
    if ((l & 7) == 0) den[(size_t)v * 16 + head] = dn;
}

__global__ void gat_fin4(const float* __restrict__ den, const float* __restrict__ res,
                         float* __restrict__ num, int n)
{
    int gid = blockIdx.x * blockDim.x + threadIdx.x;
    if (gid >= n * 128) return;
    int v = gid >> 7, l = gid & 127, head = l >> 3;
    float d = den[(size_t)v * 16 + head];
    float inv = (d > 0.f) ? __fdividef(1.f, d) : 0.f;
    float4 o = reinterpret_cast<float4*>(num)[gid];
    float4 r = reinterpret_cast<const float4*>(res)[gid];
    o.x = fmaxf(o.x * inv + r.x, 0.f);
    o.y = fmaxf(o.y * inv + r.y, 0.f);
    o.z = fmaxf(o.z * inv + r.z, 0.f);
    o.w = fmaxf(o.w * inv + r.w, 0.f);
    reinterpret_cast<float4*>(num)[gid] = o;
}

// ---------------- final classifier
__global__ void final_lin(const float* __restrict__ h1, const float* __restrict__ newF,
                          const float* __restrict__ h3, const float* __restrict__ W,
                          const float* __restrict__ bias, float* __restrict__ out, int n)
{
    int gid = blockIdx.x * blockDim.x + threadIdx.x;
    if (gid >= n * 6) return;
    int v = gid / 6, o = gid - v * 6;
    float s = bias[o];
    const float* a = h1 + (size_t)v * 64;
#pragma unroll 8
    for (int r = 0; r < 64; ++r) s += a[r] * W[r * 6 + o];
    const float* b = newF + (size_t)v * 8;
#pragma unroll
    for (int r = 0; r < 8; ++r) s += b[r] * W[(64 + r) * 6 + o];
    const float* c = h3 + (size_t)v * 64;
#pragma unroll 8
    for (int r = 0; r < 64; ++r) s += c[r] * W[(72 + r) * 6 + o];
    out[gid] = s;
}

// ----------------------------------------------------------------------------
extern "C" void kernel_launch(void* const* d_in, const int* in_sizes, int n_in,
                              void* d_out, int out_size, void* d_ws, size_t ws_size,
                              hipStream_t stream)
{
    const float* text   = (const float*)d_in[0];
    const float* audio  = (const float*)d_in[1];
    const float* vision = (const float*)d_in[2];
    const int*   esrc   = (const int*)d_in[3];
    const int*   edst   = (const int*)d_in[4];
    const float* W_audio = (const float*)d_in[5];  const float* b_audio = (const float*)d_in[6];
    const float* W_vision= (const float*)d_in[7];  const float* b_vision= (const float*)d_in[8];
    const float* W_text  = (const float*)d_in[9];  const float* b_text  = (const float*)d_in[10];
    const float* Wih_f = (const float*)d_in[11]; const float* Whh_f = (const float*)d_in[12];
    const float* bih_f = (const float*)d_in[13]; const float* bhh_f = (const float*)d_in[14];
    const float* Wih_b = (const float*)d_in[15]; const float* Whh_b = (const float*)d_in[16];
    const float* bih_b = (const float*)d_in[17]; const float* bhh_b = (const float*)d_in[18];
    const float* W_gc  = (const float*)d_in[19]; const float* b_gc  = (const float*)d_in[20];
    const float* Wsrc2 = (const float*)d_in[21]; const float* bsrc2 = (const float*)d_in[22];
    const float* Wdst2 = (const float*)d_in[23]; const float* bdst2 = (const float*)d_in[24];
    const float* attn2 = (const float*)d_in[25]; const float* Wres2 = (const float*)d_in[26];
    const float* Wsrc0 = (const float*)d_in[27]; const float* bsrc0 = (const float*)d_in[28];
    const float* Wdst0 = (const float*)d_in[29]; const float* bdst0 = (const float*)d_in[30];
    const float* attn0 = (const float*)d_in[31]; const float* Wres0 = (const float*)d_in[32];
    const float* Wsrc1 = (const float*)d_in[33]; const float* bsrc1 = (const float*)d_in[34];
    const float* Wdst1 = (const float*)d_in[35]; const float* bdst1 = (const float*)d_in[36];
    const float* attn1 = (const float*)d_in[37]; const float* Wres1 = (const float*)d_in[38];
    const float* W_lin = (const float*)d_in[39]; const float* b_lin = (const float*)d_in[40];
    float* out = (float*)d_out;

    const int n = in_sizes[0] / 1024;   // 12000
    const int E = in_sizes[3];          // 192000
    const int B = n / 120;              // 100

    // ---- workspace carve (256B aligned) — layout unchanged
    char* p = (char*)d_ws;
    auto alloc_f = [&](size_t cnt) { float* r = (float*)p; p += ((cnt * 4 + 255) / 256) * 256; return r; };
    auto alloc_i = [&](size_t cnt) { int* r = (int*)p; p += ((cnt * 4 + 255) / 256) * 256; return r; };
    float* stackFT = alloc_f((size_t)n * 192);
    float* hbuf    = alloc_f((size_t)n * 192);
    float* xWf     = alloc_f((size_t)n * 16);
    float* xWb     = alloc_f((size_t)n * 16);
    float* newF    = alloc_f((size_t)n * 8);
    float* big0    = alloc_f((size_t)n * 512);   // gat0: bf16 fs|fd [n,1024] fits in half
    float* big1    = alloc_f((size_t)n * 512);   // res0 f32 [n,512]
    float* big2    = alloc_f((size_t)n * 512);   // num0 -> h0 f32 [n,512]
    float* den     = alloc_f((size_t)n * 16);
    float* h3      = alloc_f((size_t)n * 64);
    float* h1s     = alloc_f((size_t)n * 64);    // doubles as packed-weight scratch until gat1 edge
    float* rs_out  = alloc_f(n);
    float* rs_in   = alloc_f(n);
    int* zero_base = alloc_i((size_t)3 * n);
    int* degout = zero_base;
    int* degin  = zero_base + n;
    int* cursor = zero_base + 2 * n;
    int* rowstart = alloc_i((size_t)n + 1);
    int* perm     = alloc_i((size_t)E);
    if ((size_t)(p - (char*)d_ws) > ws_size) return;

    float* pw = h1s;
    float* pb = h1s + 200704;

    // ---- graph preprocessing
    hipMemsetAsync(zero_base, 0, (size_t)3 * n * 4, stream);
    deg_kernel<<<(E + 255) / 256, 256, 0, stream>>>(esrc, edst, degout, degin, E);
    scan_kernel<<<1, 1024, 0, stream>>>(degin, rowstart, n);
    perm_kernel<<<(E + 255) / 256, 256, 0, stream>>>(edst, rowstart, cursor, perm, E);
    gather_src_kernel<<<(E + 255) / 256, 256, 0, stream>>>(esrc, perm, E);
    rs_kernel<<<(n + 255) / 256, 256, 0, stream>>>(degout, degin, rs_out, rs_in, n);
    const int* csrc = perm;

    auto mgemm = [&](const float* A, const float* Bm, const float* bias, const float* rsc,
                     float* Cp, int M, int Nb, int K, int ldc) {
        dim3 grid((M + 127) / 128, Nb / 64);
        mfma_gemm<false><<<grid, 256, 0, stream>>>(A, Bm, bias, rsc, Cp, M, Nb, K, ldc, 0);
    };
    auto mgemm_bf = [&](const float* A, const float* Bm, const float* bias,
                        unsigned short* Cp, int M, int Nb, int K, int ldc) {
        dim3 grid((M + 127) / 128, Nb / 64);
        mfma_gemm<true><<<grid, 256, 0, stream>>>(A, Bm, bias, nullptr, Cp, M, Nb, K, ldc, 0);
    };

    // ---- modality encoders -> stackFT [n,192] (bf16x3 MFMA, ~f32 accuracy)
    {
        dim3 grid((n + 63) / 64, 1, 3);
        enc_mfma<<<grid, 256, 0, stream>>>(text, audio, vision, W_text, W_audio, W_vision,
                                           b_text, b_audio, b_vision, stackFT, n);
    }

    // ---- BiLSTM
    lstm_pre<<<(n * 32 + 255) / 256, 256, 0, stream>>>(stackFT, Wih_f, Wih_b,
                                                       bih_f, bhh_f, bih_b, bhh_b, xWf, xWb, n);
    lstm_seq2<<<(2 * B + 3) / 4, 64, 0, stream>>>(xWf, xWb, Whh_f, Whh_b, newF, B);

    // ---- GraphConv imputation + L1 norm -> hbuf
    mgemm(stackFT, W_gc, nullptr, rs_out, big0, n, 192, 192, 192);
    gc_combine2<<<(n + 3) / 4, 256, 0, stream>>>(stackFT, big0, rowstart, csrc, rs_in, b_gc, hbuf, n);

    // ---- gat2: packed src|dst|res GEMM -> stackFT [n,192], fused edge -> h3
    pack3_kernel<<<(192 * 192 + 255) / 256, 256, 0, stream>>>(Wsrc2, Wdst2, Wres2, bsrc2, bdst2, pw, pb, 192, 64);
    mgemm(hbuf, pw, pb, nullptr, stackFT, n, 192, 192, 192);
    gat_edge4<<<(n + 15) / 16, 256, 0, stream>>>(stackFT, 192, attn2, rowstart, csrc, h3, n);

    // ---- gat0: packed src|dst GEMM -> big0 bf16 [n,1024]; edge -> big2; res GEMM -> big1; fin
    pack2_kernel<<<(192 * 1024 + 255) / 256, 256, 0, stream>>>(Wsrc0, Wdst0, bsrc0, bdst0, pw, pb, 192, 512);
    mgemm_bf(hbuf, pw, pb, (unsigned short*)big0, n, 1024, 192, 1024);
    gat_edge32<<<(n + 1) / 2, 256, 0, stream>>>((const unsigned short*)big0, attn0, rowstart, csrc, big2, den, n);
    mgemm(hbuf, Wres0, nullptr, nullptr, big1, n, 512, 192, 512);
    gat_fin4<<<(n * 128 + 255) / 256, 256, 0, stream>>>(den, big1, big2, n);

    // ---- gat1: packed src|dst|res GEMM -> big0 f32 [n,192], fused edge -> h1s
    pack3_kernel<<<(512 * 192 + 255) / 256, 256, 0, stream>>>(Wsrc1, Wdst1, Wres1, bsrc1, bdst1, pw, pb, 512, 64);
    mgemm(big2, pw, pb, nullptr, big0, n, 192, 512, 192);
    gat_edge4<<<(n + 15) / 16, 256, 0, stream>>>(big0, 192, attn1, rowstart, csrc, h1s, n);

    // ---- final classifier
    final_lin<<<(n * 6 + 255) / 256, 256, 0, stream>>>(h1s, newF, h3, W_lin, b_lin, out, n);
}